// Round 4
// baseline (753.121 us; speedup 1.0000x reference)
//
#include <hip/hip_runtime.h>
#include <math.h>

constexpr float EPS = 1e-5f;
constexpr float SCALE = 0.08838834764831845f; // 1/sqrt(128)

using f32x4  = __attribute__((ext_vector_type(4))) float;
using bf16x8 = __attribute__((ext_vector_type(8))) short;
using us8    = __attribute__((ext_vector_type(8))) unsigned short;

__device__ __forceinline__ unsigned short f2b_rne(float f) {
    unsigned int x = __float_as_uint(f);
    return (unsigned short)((x + 0x7fffu + ((x >> 16) & 1u)) >> 16);
}

// XOR-swizzled element offset into a [rows][32]-us tile; k8 = 8-elem col chunk.
__device__ __forceinline__ int swz32(int row, int k8) {
    int f = (row & 3) ^ ((row >> 2) & 3);
    return row * 32 + ((k8 ^ f) << 3);
}

// ====== one-time weight prep: bf16 hi/lo split (Wp|Wk|Wv) + float4 T-pack ====
// hi/lo: Wp (24576) | Wk (16384) | Wv (16384).
// wt4:   WihT4[0,12288) WhhT4[12288,24576) W1T4[24576,32768)
//        W2T4[32768,40960) WqT4[40960,45056)  -- W[out][K] -> [K/4][out] f4.
__global__ __launch_bounds__(256) void prep_weights_kernel(
    const float* __restrict__ Wp, const float* __restrict__ Wk,
    const float* __restrict__ Wv, const float* __restrict__ Wih,
    const float* __restrict__ Whh, const float* __restrict__ W1,
    const float* __restrict__ W2, const float* __restrict__ Wq,
    unsigned short* __restrict__ hi, unsigned short* __restrict__ lo,
    float4* __restrict__ wt4)
{
    int idx = blockIdx.x * 256 + threadIdx.x; // 102400 total
    if (idx < 57344) {
        float v;
        if (idx < 24576)      v = Wp[idx];
        else if (idx < 40960) v = Wk[idx - 24576];
        else                  v = Wv[idx - 40960];
        unsigned int bits = __float_as_uint(v);
        hi[idx] = (unsigned short)(bits >> 16);
        lo[idx] = f2b_rne(v - __uint_as_float(bits & 0xffff0000u));
    } else {
        int li = idx - 57344;
        const float* src; int OUT, base, K;
        if (li < 12288)      { src = Wih; OUT = 384; base = 0;     K = 128; }
        else if (li < 24576) { src = Whh; OUT = 384; base = 12288; K = 128; }
        else if (li < 32768) { src = W1;  OUT = 256; base = 24576; K = 128; }
        else if (li < 40960) { src = W2;  OUT = 128; base = 32768; K = 256; }
        else                 { src = Wq;  OUT = 128; base = 40960; K = 128; }
        int lo2 = li - base;
        int kq = lo2 / OUT, t = lo2 - kq * OUT;
        float4 v;
        v.x = src[(size_t)t * K + 4 * kq];
        v.y = src[(size_t)t * K + 4 * kq + 1];
        v.z = src[(size_t)t * K + 4 * kq + 2];
        v.w = src[(size_t)t * K + 4 * kq + 3];
        wt4[li] = v;
    }
}

// ========== mega-fused: X = LN(patch @ Wp^T + bp); k,v = X @ {Wk,Wv}^T =======
// 48 KB LDS -> 3 blocks/CU. Whole patch tile preloaded to registers (removes
// the per-K-step HBM round-trip from the critical path); K-loop fully unrolled.
__global__ __launch_bounds__(256, 3) void fused_proj_kv_kernel(
    const float* __restrict__ patch,
    const unsigned short* __restrict__ Wphi, const unsigned short* __restrict__ Wplo,
    const unsigned short* __restrict__ Wkhi, const unsigned short* __restrict__ Wklo,
    const unsigned short* __restrict__ Wvhi, const unsigned short* __restrict__ Wvlo,
    const float* __restrict__ biasp, const float* __restrict__ g_in,
    const float* __restrict__ b_in, const float* __restrict__ biask,
    const float* __restrict__ biasv,
    float* __restrict__ kout, float* __restrict__ vout)
{
    // mem layout (48 KB):
    //  phase 1: Ah[0,2048) Al[2048,4096) Bh[4096,8192) Bl[8192,12288)
    //  X (after phase 1): Xh[0,8192) Xl[8192,16384)
    //  phase 2 weights: Wh[16384,20480) Wl[20480,24576)
    __shared__ __align__(16) unsigned short mem[24576];

    const int tid  = threadIdx.x;
    const int lane = tid & 63, wave = tid >> 6;
    const int ln15 = lane & 15, quad = lane >> 4;
    const int m0   = blockIdx.x * 64;

    // ---------------- phase 1: X = LN(patch @ Wp^T + bp) ----------------
    const int wrow = wave * 16;                 // wave owns 16 rows
    f32x4 acc1[8];
#pragma unroll
    for (int nt = 0; nt < 8; nt++)
#pragma unroll
        for (int r = 0; r < 4; r++) acc1[nt][r] = 0.f;

    const int arow = tid >> 2, ak8 = tid & 3;   // A: 1 chunk/thread (64x32)
    const float* aptr = patch + (size_t)(m0 + arow) * 192 + ak8 * 8;
    // preload the whole 64x192 patch tile: 12 float4/thread, one burst
    float4 pa[6][2];
#pragma unroll
    for (int t6 = 0; t6 < 6; t6++) {
        pa[t6][0] = *(const float4*)(aptr + t6 * 32);
        pa[t6][1] = *(const float4*)(aptr + t6 * 32 + 4);
    }
    us8 pbh[2], pbl[2];                          // B: 2 chunks/thread (128x32)
    int boff[2];
#pragma unroll
    for (int i = 0; i < 2; i++) {
        int c = tid + 256 * i;
        boff[i] = (c >> 2) * 192 + (c & 3) * 8;
        pbh[i] = *(const us8*)(Wphi + boff[i]);
        pbl[i] = *(const us8*)(Wplo + boff[i]);
    }

    const int ea = swz32(wrow + ln15, quad);

#pragma unroll
    for (int st = 0; st < 6; st++) {
        {
            float va[8] = {pa[st][0].x, pa[st][0].y, pa[st][0].z, pa[st][0].w,
                           pa[st][1].x, pa[st][1].y, pa[st][1].z, pa[st][1].w};
            us8 h, l;
#pragma unroll
            for (int j = 0; j < 8; j++) {
                unsigned int bits = __float_as_uint(va[j]);
                h[j] = (unsigned short)(bits >> 16);
                l[j] = f2b_rne(va[j] - __uint_as_float(bits & 0xffff0000u));
            }
            int e = swz32(arow, ak8);
            *(us8*)&mem[e]        = h;
            *(us8*)&mem[2048 + e] = l;
        }
#pragma unroll
        for (int i = 0; i < 2; i++) {
            int c = tid + 256 * i;
            int e = swz32(c >> 2, c & 3);
            *(us8*)&mem[4096 + e] = pbh[i];
            *(us8*)&mem[8192 + e] = pbl[i];
        }
        __syncthreads();

        if (st < 5) {
            int kn = (st + 1) * 32;
#pragma unroll
            for (int i = 0; i < 2; i++) {
                pbh[i] = *(const us8*)(Wphi + boff[i] + kn);
                pbl[i] = *(const us8*)(Wplo + boff[i] + kn);
            }
        }

        bf16x8 ah = *(const bf16x8*)&mem[ea];
        bf16x8 al = *(const bf16x8*)&mem[2048 + ea];
#pragma unroll
        for (int nt = 0; nt < 8; nt++) {
            int eb = swz32(nt * 16 + ln15, quad);
            bf16x8 bh = *(const bf16x8*)&mem[4096 + eb];
            bf16x8 bl = *(const bf16x8*)&mem[8192 + eb];
            acc1[nt] = __builtin_amdgcn_mfma_f32_16x16x32_bf16(ah, bh, acc1[nt], 0, 0, 0);
            acc1[nt] = __builtin_amdgcn_mfma_f32_16x16x32_bf16(ah, bl, acc1[nt], 0, 0, 0);
            acc1[nt] = __builtin_amdgcn_mfma_f32_16x16x32_bf16(al, bh, acc1[nt], 0, 0, 0);
        }
        __syncthreads();
    }

    // prefetch phase-2 step-0 weights (k-pass, kk=0): latency hides under LN
    us8 pw[4];
#pragma unroll
    for (int i = 0; i < 4; i++) {
        const unsigned short* pl = (i >> 1) ? Wklo : Wkhi;
        int c = tid + (i & 1) * 256;
        pw[i] = *(const us8*)(pl + (size_t)(c >> 2) * 128 + (c & 3) * 8);
    }

    // ---- LN epilogue -> X hi/lo into LDS (aliases dead phase-1 staging) ----
    {
        float bb[8], gg[8], be[8];
#pragma unroll
        for (int nt = 0; nt < 8; nt++) {
            int col = nt * 16 + ln15;
            bb[nt] = biasp[col]; gg[nt] = g_in[col]; be[nt] = b_in[col];
        }
#pragma unroll
        for (int nt = 0; nt < 8; nt++)
#pragma unroll
            for (int r = 0; r < 4; r++) acc1[nt][r] += bb[nt];

        float mu[4], rs[4];
#pragma unroll
        for (int r = 0; r < 4; r++) {
            float s = 0.f, s2 = 0.f;
#pragma unroll
            for (int nt = 0; nt < 8; nt++) {
                float v = acc1[nt][r];
                s += v; s2 += v * v;
            }
#pragma unroll
            for (int off = 1; off < 16; off <<= 1) {
                s  += __shfl_xor(s,  off, 64);
                s2 += __shfl_xor(s2, off, 64);
            }
            float m = s * (1.f / 128.f);
            mu[r] = m;
            rs[r] = rsqrtf(s2 * (1.f / 128.f) - m * m + EPS);
        }
#pragma unroll
        for (int nt = 0; nt < 8; nt++)
#pragma unroll
            for (int r = 0; r < 4; r++) {
                float v = (acc1[nt][r] - mu[r]) * rs[r] * gg[nt] + be[nt];
                int row = wrow + quad * 4 + r, col = nt * 16 + ln15;
                int xi = (row * 128 + col) ^ ((row & 7) << 3);
                unsigned int bits = __float_as_uint(v);
                mem[xi]        = (unsigned short)(bits >> 16);
                mem[8192 + xi] = f2b_rne(v - __uint_as_float(bits & 0xffff0000u));
            }
    }

    // ---------------- phase 2: k-pass (s=0..3) then v-pass (s=4..7) -------
    const int R  = (wave & 1) * 32;
    const int Cb = (wave >> 1) * 64;
    const int xorx = (ln15 & 7) << 3;

    float bbk[4], bbv[4];
#pragma unroll
    for (int nt = 0; nt < 4; nt++) {
        int col = Cb + nt * 16 + ln15;
        bbk[nt] = biask[col];
        bbv[nt] = biasv[col];
    }

    f32x4 acc[2][4];
#pragma unroll
    for (int mt = 0; mt < 2; mt++)
#pragma unroll
        for (int nt = 0; nt < 4; nt++)
#pragma unroll
            for (int r = 0; r < 4; r++) acc[mt][nt][r] = 0.f;

#pragma unroll
    for (int s = 0; s < 8; s++) {
#pragma unroll
        for (int i = 0; i < 4; i++) {
            int c = tid + (i & 1) * 256;
            int e = 16384 + (i >> 1) * 4096 + swz32(c >> 2, c & 3);
            *(us8*)&mem[e] = pw[i];
        }
        __syncthreads();

        if (s < 7) {
            int sn = s + 1, kkn = (sn & 3) * 32;
            const unsigned short* ph = (sn >> 2) ? Wvhi : Wkhi;
            const unsigned short* po = (sn >> 2) ? Wvlo : Wklo;
#pragma unroll
            for (int i = 0; i < 4; i++) {
                const unsigned short* pl = (i >> 1) ? po : ph;
                int c = tid + (i & 1) * 256;
                pw[i] = *(const us8*)(pl + (size_t)(c >> 2) * 128 + (c & 3) * 8 + kkn);
            }
        }

        int kk = (s & 3) * 32;
        bf16x8 xh[2], xl[2];
#pragma unroll
        for (int mt = 0; mt < 2; mt++) {
            int row = R + mt * 16 + ln15;
            int ei = (row * 128 + kk + quad * 8) ^ xorx;
            xh[mt] = *(const bf16x8*)&mem[ei];
            xl[mt] = *(const bf16x8*)&mem[8192 + ei];
        }
#pragma unroll
        for (int nt = 0; nt < 4; nt++) {
            int eb = 16384 + swz32(Cb + nt * 16 + ln15, quad);
            bf16x8 wh = *(const bf16x8*)&mem[eb];
            bf16x8 wl = *(const bf16x8*)&mem[4096 + eb];
#pragma unroll
            for (int mt = 0; mt < 2; mt++) {
                acc[mt][nt] = __builtin_amdgcn_mfma_f32_16x16x32_bf16(xh[mt], wh, acc[mt][nt], 0, 0, 0);
                acc[mt][nt] = __builtin_amdgcn_mfma_f32_16x16x32_bf16(xh[mt], wl, acc[mt][nt], 0, 0, 0);
                acc[mt][nt] = __builtin_amdgcn_mfma_f32_16x16x32_bf16(xl[mt], wh, acc[mt][nt], 0, 0, 0);
            }
        }

        if (s == 3) { // k epilogue; reuse accumulators for v
#pragma unroll
            for (int mt = 0; mt < 2; mt++)
#pragma unroll
                for (int nt = 0; nt < 4; nt++)
#pragma unroll
                    for (int r = 0; r < 4; r++) {
                        size_t o = (size_t)(m0 + R + mt * 16 + quad * 4 + r) * 128
                                 + Cb + nt * 16 + ln15;
                        kout[o] = acc[mt][nt][r] + bbk[nt];
                        acc[mt][nt][r] = 0.f;
                    }
        }
        if (s < 7) __syncthreads();
    }

#pragma unroll
    for (int mt = 0; mt < 2; mt++)
#pragma unroll
        for (int nt = 0; nt < 4; nt++)
#pragma unroll
            for (int r = 0; r < 4; r++) {
                size_t o = (size_t)(m0 + R + mt * 16 + quad * 4 + r) * 128
                         + Cb + nt * 16 + ln15;
                vout[o] = acc[mt][nt][r] + bbv[nt];
            }
}

// ====== mega-fused iteration loop: one block per batch, all 3 iterations =====
// Per iteration: LN_s+q -> attention (8x128-token chunks, dbuf k/v in regs)
// -> GRU -> LN_m -> MLP -> residual. No global sync needed: batches are
// independent (softmax is over slots). upd/q/slots round-trips eliminated.
__global__ __launch_bounds__(512, 1) void slot_iter_kernel(
    const float* __restrict__ noise, const float* __restrict__ smu,
    const float* __restrict__ sls,
    const float* __restrict__ g_s, const float* __restrict__ b_s,
    const float4* __restrict__ WqT4, const float* __restrict__ bq,
    const float* __restrict__ kbuf, const float* __restrict__ vbuf,
    const float4* __restrict__ WihT4, const float* __restrict__ bih,
    const float4* __restrict__ WhhT4, const float* __restrict__ bhh,
    const float* __restrict__ g_m, const float* __restrict__ b_m,
    const float4* __restrict__ W1T4, const float* __restrict__ b1,
    const float4* __restrict__ W2T4, const float* __restrict__ b2,
    float* __restrict__ out_slots, float* __restrict__ out_attn)
{
    __shared__ float q_l[3][132];
    __shared__ float h_l[3][128];   // current slots
    __shared__ float u_l[3][128];   // updates
    __shared__ float hn2[3][128];   // hnew
    __shared__ float n_l[3][128];   // LN output
    __shared__ float r_l[3][128], z_l[3][128], in_l[3][128], hnl[3][128];
    __shared__ float part[16][3][128];
    __shared__ float lg[3][128], w_l[3][128];
    __shared__ float hid_l[3][256];
    __shared__ float w2p[2][3][128];
    __shared__ float red[3][4];

    const int b = blockIdx.x, tid = threadIdx.x;

    const float* kb_ = kbuf + (size_t)b * 131072;
    const float* vb_ = vbuf + (size_t)b * 131072;
    // k layout: token = c*128 + (tid>>2), quarter (tid&3)*32, 8xfloat4/chunk
    const float4* kp4 = (const float4*)(kb_ + (size_t)(tid >> 2) * 128 + (tid & 3) * 32);
    // v layout: token group tg = tid>>5 (8 tokens), d0 = (tid&31)*4
    const float* vp = vb_ + (size_t)(tid >> 5) * 1024 + (tid & 31) * 4;

    // ---- slots init ----
    if (tid < 384) {
        int s = tid >> 7, d = tid & 127;
        float x = smu[s * 128 + d] + expf(sls[s * 128 + d]) * noise[(size_t)b * 384 + tid];
        h_l[s][d] = x;
    }
    __syncthreads();

    float4 ka[8], kb2[8], va[8], vb2[8];
    float4 acc0, acc1, acc2;

    // per-chunk attention body: prefetch next, logits, softmax, PV
    auto attn_chunk = [&](int c, float4 (&kc)[8], float4 (&vc)[8],
                          float4 (&kn)[8], float4 (&vn)[8], bool pf, bool wout) {
        if (pf) {
            const float4* kpn = kp4 + (c + 1) * 4096;
            const float* vpn = vp + (c + 1) * 16384;
#pragma unroll
            for (int i = 0; i < 8; i++) kn[i] = kpn[i];
#pragma unroll
            for (int j = 0; j < 8; j++) vn[j] = *(const float4*)(vpn + j * 128);
        }
        { // logits: thread = (token tid>>2, quarter tid&3)
            const float* q0 = &q_l[0][(tid & 3) * 33];
            const float* q1 = &q_l[1][(tid & 3) * 33];
            const float* q2 = &q_l[2][(tid & 3) * 33];
            float p0 = 0.f, p1 = 0.f, p2 = 0.f;
#pragma unroll
            for (int i = 0; i < 8; i++) {
                float kx[4] = {kc[i].x, kc[i].y, kc[i].z, kc[i].w};
#pragma unroll
                for (int j = 0; j < 4; j++) {
                    float vv = kx[j];
                    p0 += q0[4 * i + j] * vv;
                    p1 += q1[4 * i + j] * vv;
                    p2 += q2[4 * i + j] * vv;
                }
            }
            p0 += __shfl_xor(p0, 1, 64); p0 += __shfl_xor(p0, 2, 64);
            p1 += __shfl_xor(p1, 1, 64); p1 += __shfl_xor(p1, 2, 64);
            p2 += __shfl_xor(p2, 1, 64); p2 += __shfl_xor(p2, 2, 64);
            if ((tid & 3) == 0) {
                int n = tid >> 2;
                lg[0][n] = p0 * SCALE; lg[1][n] = p1 * SCALE; lg[2][n] = p2 * SCALE;
            }
        }
        __syncthreads();
        if (tid < 128) { // softmax over slots for token tid
            float l0 = lg[0][tid], l1 = lg[1][tid], l2 = lg[2][tid];
            float m = fmaxf(l0, fmaxf(l1, l2));
            float e0 = expf(l0 - m), e1 = expf(l1 - m), e2 = expf(l2 - m);
            float inv = 1.f / (e0 + e1 + e2);
            w_l[0][tid] = e0 * inv; w_l[1][tid] = e1 * inv; w_l[2][tid] = e2 * inv;
            if (wout) {
                int n = c * 128 + tid;
                out_attn[b * 3072 + n]        = e0 * inv;
                out_attn[b * 3072 + 1024 + n] = e1 * inv;
                out_attn[b * 3072 + 2048 + n] = e2 * inv;
            }
        }
        __syncthreads();
        { // PV: thread accumulates 4 d-cols over its 8 tokens
            int tg = tid >> 5;
#pragma unroll
            for (int j = 0; j < 8; j++) {
                float w0 = w_l[0][tg * 8 + j];
                float w1 = w_l[1][tg * 8 + j];
                float w2 = w_l[2][tg * 8 + j];
                float4 vv = vc[j];
                acc0.x += w0 * vv.x; acc0.y += w0 * vv.y; acc0.z += w0 * vv.z; acc0.w += w0 * vv.w;
                acc1.x += w1 * vv.x; acc1.y += w1 * vv.y; acc1.z += w1 * vv.z; acc1.w += w1 * vv.w;
                acc2.x += w2 * vv.x; acc2.y += w2 * vv.y; acc2.z += w2 * vv.z; acc2.w += w2 * vv.w;
            }
        }
        __syncthreads(); // protect w_l before next chunk's softmax
    };

    for (int it = 0; it < 3; ++it) {
        const bool last = (it == 2);

        // issue chunk-0 k/v loads early: latency hides under the q-phase
#pragma unroll
        for (int i = 0; i < 8; i++) ka[i] = kp4[i];
#pragma unroll
        for (int j = 0; j < 8; j++) va[j] = *(const float4*)(vp + j * 128);

        // ---- q-phase: s = LN(slots); q = s @ Wq^T + bq ----
        if (tid < 384) {
            int s = tid >> 7;
            float x = h_l[s][tid & 127];
            float s1 = x, s2 = x * x;
#pragma unroll
            for (int off = 1; off < 64; off <<= 1) {
                s1 += __shfl_xor(s1, off, 64); s2 += __shfl_xor(s2, off, 64);
            }
            if ((tid & 63) == 0) {
                int wv = (tid >> 6) & 1;
                red[s][wv] = s1; red[s][2 + wv] = s2;
            }
        }
        __syncthreads();
        if (tid < 384) {
            int s = tid >> 7, d = tid & 127;
            float S = red[s][0] + red[s][1], S2 = red[s][2] + red[s][3];
            float m = S * (1.f / 128.f);
            float r = rsqrtf(S2 * (1.f / 128.f) - m * m + EPS);
            n_l[s][d] = (h_l[s][d] - m) * r * g_s[d] + b_s[d];
        }
        __syncthreads();
        if (tid < 256) { // Wq, K split in halves
            int out = tid & 127, half = tid >> 7;
            float p0 = half ? 0.f : bq[out], p1 = p0, p2 = p0;
#pragma unroll
            for (int kq = half * 16; kq < half * 16 + 16; kq++) {
                float4 w = WqT4[kq * 128 + out];
                p0 += n_l[0][4 * kq] * w.x + n_l[0][4 * kq + 1] * w.y
                    + n_l[0][4 * kq + 2] * w.z + n_l[0][4 * kq + 3] * w.w;
                p1 += n_l[1][4 * kq] * w.x + n_l[1][4 * kq + 1] * w.y
                    + n_l[1][4 * kq + 2] * w.z + n_l[1][4 * kq + 3] * w.w;
                p2 += n_l[2][4 * kq] * w.x + n_l[2][4 * kq + 1] * w.y
                    + n_l[2][4 * kq + 2] * w.z + n_l[2][4 * kq + 3] * w.w;
            }
            w2p[half][0][out] = p0; w2p[half][1][out] = p1; w2p[half][2][out] = p2;
        }
        __syncthreads();
        if (tid < 384) {
            int s = tid >> 7, d = tid & 127;
            float qv = w2p[0][s][d] + w2p[1][s][d];
            q_l[s][d + (d >> 5)] = qv;
        }
        __syncthreads();

        // ---- attention: 8 chunks of 128 tokens ----
        acc0 = {0.f, 0.f, 0.f, 0.f}; acc1 = acc0; acc2 = acc0;
        attn_chunk(0, ka, va, kb2, vb2, true, last);
        attn_chunk(1, kb2, vb2, ka, va, true, last);
        attn_chunk(2, ka, va, kb2, vb2, true, last);
        attn_chunk(3, kb2, vb2, ka, va, true, last);
        attn_chunk(4, ka, va, kb2, vb2, true, last);
        attn_chunk(5, kb2, vb2, ka, va, true, last);
        attn_chunk(6, ka, va, kb2, vb2, true, last);
        attn_chunk(7, kb2, vb2, ka, va, false, last);

        { // reduce PV partials -> u_l
            int tg = tid >> 5, d0 = (tid & 31) * 4;
            *(float4*)&part[tg][0][d0] = acc0;
            *(float4*)&part[tg][1][d0] = acc1;
            *(float4*)&part[tg][2][d0] = acc2;
        }
        __syncthreads();
        if (tid < 384) {
            int s = tid >> 7, d = tid & 127;
            float u = 0.f;
#pragma unroll
            for (int tg = 0; tg < 16; tg++) u += part[tg][s][d];
            u_l[s][d] = u;
        }
        __syncthreads();

        // ---- GRU gates: thread = gate-output, reused across 3 slots ----
        if (tid < 384) {
            float gi0 = bih[tid], gi1 = gi0, gi2 = gi0;
            float gh0 = bhh[tid], gh1 = gh0, gh2 = gh0;
#pragma unroll 8
            for (int kq = 0; kq < 32; kq++) {
                float4 a = WihT4[kq * 384 + tid];
                float4 c4 = WhhT4[kq * 384 + tid];
                gi0 += u_l[0][4 * kq] * a.x + u_l[0][4 * kq + 1] * a.y
                     + u_l[0][4 * kq + 2] * a.z + u_l[0][4 * kq + 3] * a.w;
                gi1 += u_l[1][4 * kq] * a.x + u_l[1][4 * kq + 1] * a.y
                     + u_l[1][4 * kq + 2] * a.z + u_l[1][4 * kq + 3] * a.w;
                gi2 += u_l[2][4 * kq] * a.x + u_l[2][4 * kq + 1] * a.y
                     + u_l[2][4 * kq + 2] * a.z + u_l[2][4 * kq + 3] * a.w;
                gh0 += h_l[0][4 * kq] * c4.x + h_l[0][4 * kq + 1] * c4.y
                     + h_l[0][4 * kq + 2] * c4.z + h_l[0][4 * kq + 3] * c4.w;
                gh1 += h_l[1][4 * kq] * c4.x + h_l[1][4 * kq + 1] * c4.y
                     + h_l[1][4 * kq + 2] * c4.z + h_l[1][4 * kq + 3] * c4.w;
                gh2 += h_l[2][4 * kq] * c4.x + h_l[2][4 * kq + 1] * c4.y
                     + h_l[2][4 * kq + 2] * c4.z + h_l[2][4 * kq + 3] * c4.w;
            }
            if (tid < 128) {
                r_l[0][tid] = 1.f / (1.f + expf(-(gi0 + gh0)));
                r_l[1][tid] = 1.f / (1.f + expf(-(gi1 + gh1)));
                r_l[2][tid] = 1.f / (1.f + expf(-(gi2 + gh2)));
            } else if (tid < 256) {
                int d = tid - 128;
                z_l[0][d] = 1.f / (1.f + expf(-(gi0 + gh0)));
                z_l[1][d] = 1.f / (1.f + expf(-(gi1 + gh1)));
                z_l[2][d] = 1.f / (1.f + expf(-(gi2 + gh2)));
            } else {
                int d = tid - 256;
                in_l[0][d] = gi0; hnl[0][d] = gh0;
                in_l[1][d] = gi1; hnl[1][d] = gh1;
                in_l[2][d] = gi2; hnl[2][d] = gh2;
            }
        }
        __syncthreads();

        // ---- hnew + LN_m ----
        if (tid < 384) {
            int s = tid >> 7, d = tid & 127;
            float nn = tanhf(in_l[s][d] + r_l[s][d] * hnl[s][d]);
            float hnewv = (1.f - z_l[s][d]) * nn + z_l[s][d] * h_l[s][d];
            hn2[s][d] = hnewv;
            float s1 = hnewv, s2 = hnewv * hnewv;
#pragma unroll
            for (int off = 1; off < 64; off <<= 1) {
                s1 += __shfl_xor(s1, off, 64); s2 += __shfl_xor(s2, off, 64);
            }
            if ((tid & 63) == 0) {
                int wv = (tid >> 6) & 1;
                red[s][wv] = s1; red[s][2 + wv] = s2;
            }
        }
        __syncthreads();
        if (tid < 384) {
            int s = tid >> 7, d = tid & 127;
            float S = red[s][0] + red[s][1], S2 = red[s][2] + red[s][3];
            float m1 = S * (1.f / 128.f);
            float r1 = rsqrtf(S2 * (1.f / 128.f) - m1 * m1 + EPS);
            n_l[s][d] = (hn2[s][d] - m1) * r1 * g_m[d] + b_m[d];
        }
        __syncthreads();

        // ---- MLP W1 + gelu (weight row reused across slots) ----
        if (tid < 256) {
            float a0 = b1[tid], a1 = a0, a2 = a0;
#pragma unroll 8
            for (int kq = 0; kq < 32; kq++) {
                float4 w = W1T4[kq * 256 + tid];
                a0 += n_l[0][4 * kq] * w.x + n_l[0][4 * kq + 1] * w.y
                    + n_l[0][4 * kq + 2] * w.z + n_l[0][4 * kq + 3] * w.w;
                a1 += n_l[1][4 * kq] * w.x + n_l[1][4 * kq + 1] * w.y
                    + n_l[1][4 * kq + 2] * w.z + n_l[1][4 * kq + 3] * w.w;
                a2 += n_l[2][4 * kq] * w.x + n_l[2][4 * kq + 1] * w.y
                    + n_l[2][4 * kq + 2] * w.z + n_l[2][4 * kq + 3] * w.w;
            }
            a0 = 0.5f * a0 * (1.f + erff(a0 * 0.70710678118654752f));
            a1 = 0.5f * a1 * (1.f + erff(a1 * 0.70710678118654752f));
            a2 = 0.5f * a2 * (1.f + erff(a2 * 0.70710678118654752f));
            hid_l[0][tid] = a0; hid_l[1][tid] = a1; hid_l[2][tid] = a2;
        }
        __syncthreads();

        // ---- MLP W2 (K=256 in halves) ----
        if (tid < 256) {
            int out = tid & 127, half = tid >> 7;
            float p0 = 0.f, p1 = 0.f, p2 = 0.f;
#pragma unroll 8
            for (int kq = half * 32; kq < half * 32 + 32; kq++) {
                float4 w = W2T4[kq * 128 + out];
                p0 += hid_l[0][4 * kq] * w.x + hid_l[0][4 * kq + 1] * w.y
                    + hid_l[0][4 * kq + 2] * w.z + hid_l[0][4 * kq + 3] * w.w;
                p1 += hid_l[1][4 * kq] * w.x + hid_l[1][4 * kq + 1] * w.y
                    + hid_l[1][4 * kq + 2] * w.z + hid_l[1][4 * kq + 3] * w.w;
                p2 += hid_l[2][4 * kq] * w.x + hid_l[2][4 * kq + 1] * w.y
                    + hid_l[2][4 * kq + 2] * w.z + hid_l[2][4 * kq + 3] * w.w;
            }
            w2p[half][0][out] = p0; w2p[half][1][out] = p1; w2p[half][2][out] = p2;
        }
        __syncthreads();

        // ---- residual -> new slots ----
        if (tid < 384) {
            int s = tid >> 7, d = tid & 127;
            float snew = hn2[s][d] + b2[d] + w2p[0][s][d] + w2p[1][s][d];
            h_l[s][d] = snew;
            if (last) out_slots[b * 384 + tid] = snew;
        }
        __syncthreads();
    }
}

// ============================================================================
extern "C" void kernel_launch(void* const* d_in, const int* in_sizes, int n_in,
                              void* d_out, int out_size, void* d_ws, size_t ws_size,
                              hipStream_t stream)
{
    const float* patch   = (const float*)d_in[0];
    const float* noise   = (const float*)d_in[1];
    const float* slot_mu = (const float*)d_in[2];
    const float* slot_ls = (const float*)d_in[3];
    const float* Wp = (const float*)d_in[4];  const float* bp = (const float*)d_in[5];
    const float* g_in = (const float*)d_in[6]; const float* b_in = (const float*)d_in[7];
    const float* Wq = (const float*)d_in[8];  const float* bq = (const float*)d_in[9];
    const float* Wk = (const float*)d_in[10]; const float* bk = (const float*)d_in[11];
    const float* Wv = (const float*)d_in[12]; const float* bv = (const float*)d_in[13];
    const float* Wih = (const float*)d_in[14]; const float* bih = (const float*)d_in[15];
    const float* Whh = (const float*)d_in[16]; const float* bhh = (const float*)d_in[17];
    const float* g_s = (const float*)d_in[18]; const float* b_s = (const float*)d_in[19];
    const float* W1 = (const float*)d_in[20]; const float* b1 = (const float*)d_in[21];
    const float* W2 = (const float*)d_in[22]; const float* b2 = (const float*)d_in[23];
    const float* g_m = (const float*)d_in[24]; const float* b_m = (const float*)d_in[25];

    // ---- workspace layout ----
    float* kbuf = (float*)d_ws;                                   // 16777216 f32
    float* vbuf = kbuf + 16777216;                                // 16777216 f32
    unsigned short* w_hi = (unsigned short*)(vbuf + 16777216);    // 57344
    unsigned short* w_lo = w_hi + 57344;                          // 57344
    unsigned short* wp_hi = w_hi,        * wp_lo = w_lo;
    unsigned short* wk_hi = w_hi + 24576,* wk_lo = w_lo + 24576;
    unsigned short* wv_hi = w_hi + 40960,* wv_lo = w_lo + 40960;
    float4* wt4 = (float4*)(w_lo + 57344);                        // 45056 float4
    float4* wihT4 = wt4;
    float4* whhT4 = wt4 + 12288;
    float4* w1T4  = wt4 + 24576;
    float4* w2T4  = wt4 + 32768;
    float4* wqT4  = wt4 + 40960;

    float* out_slots = (float*)d_out;                             // (B,K,H)
    float* out_attn  = (float*)d_out + 49152;                     // (B,K,N)

    prep_weights_kernel<<<400, 256, 0, stream>>>(
        Wp, Wk, Wv, Wih, Whh, W1, W2, Wq, w_hi, w_lo, wt4);

    // X = LN(patch @ Wp^T + bp) kept in LDS; k,v written directly.
    fused_proj_kv_kernel<<<2048, 256, 0, stream>>>(
        patch, wp_hi, wp_lo, wk_hi, wk_lo, wv_hi, wv_lo,
        bp, g_in, b_in, bk, bv, kbuf, vbuf);

    // entire 3-iteration slot-attention loop: one block per batch.
    slot_iter_kernel<<<128, 512, 0, stream>>>(
        noise, slot_mu, slot_ls, g_s, b_s, wqT4, bq, kbuf, vbuf,
        wihT4, bih, whhT4, bhh, g_m, b_m, w1T4, b1, w2T4, b2,
        out_slots, out_attn);
}

// Round 5
// 560.417 us; speedup vs baseline: 1.3439x; 1.3439x over previous
//
#include <hip/hip_runtime.h>
#include <math.h>

constexpr float EPS = 1e-5f;
constexpr float SCALE = 0.08838834764831845f; // 1/sqrt(128)

using f32x4  = __attribute__((ext_vector_type(4))) float;
using bf16x8 = __attribute__((ext_vector_type(8))) short;
using us8    = __attribute__((ext_vector_type(8))) unsigned short;

__device__ __forceinline__ unsigned short f2b_rne(float f) {
    unsigned int x = __float_as_uint(f);
    return (unsigned short)((x + 0x7fffu + ((x >> 16) & 1u)) >> 16);
}

// ====== one-time weight prep: bf16 hi/lo split (Wp|Wk|Wv) + float4 T-pack ====
__global__ __launch_bounds__(256) void prep_weights_kernel(
    const float* __restrict__ Wp, const float* __restrict__ Wk,
    const float* __restrict__ Wv, const float* __restrict__ Wih,
    const float* __restrict__ Whh, const float* __restrict__ W1,
    const float* __restrict__ W2, const float* __restrict__ Wq,
    unsigned short* __restrict__ hi, unsigned short* __restrict__ lo,
    float4* __restrict__ wt4)
{
    int idx = blockIdx.x * 256 + threadIdx.x; // 102400 total
    if (idx < 57344) {
        float v;
        if (idx < 24576)      v = Wp[idx];
        else if (idx < 40960) v = Wk[idx - 24576];
        else                  v = Wv[idx - 40960];
        unsigned int bits = __float_as_uint(v);
        hi[idx] = (unsigned short)(bits >> 16);
        lo[idx] = f2b_rne(v - __uint_as_float(bits & 0xffff0000u));
    } else {
        int li = idx - 57344;
        const float* src; int OUT, base, K;
        if (li < 12288)      { src = Wih; OUT = 384; base = 0;     K = 128; }
        else if (li < 24576) { src = Whh; OUT = 384; base = 12288; K = 128; }
        else if (li < 32768) { src = W1;  OUT = 256; base = 24576; K = 128; }
        else if (li < 40960) { src = W2;  OUT = 128; base = 32768; K = 256; }
        else                 { src = Wq;  OUT = 128; base = 40960; K = 128; }
        int lo2 = li - base;
        int kq = lo2 / OUT, t = lo2 - kq * OUT;
        float4 v;
        v.x = src[(size_t)t * K + 4 * kq];
        v.y = src[(size_t)t * K + 4 * kq + 1];
        v.z = src[(size_t)t * K + 4 * kq + 2];
        v.w = src[(size_t)t * K + 4 * kq + 3];
        wt4[li] = v;
    }
}

// ========== mega-fused: X = LN(patch @ Wp^T + bp); k,v = X @ {Wk,Wv}^T =======
// Barrier-diet redesign: only A (patch) staged in LDS (64x64 super-steps,
// 6 barriers); Wp/Wk/Wv MFMA fragments read DIRECTLY from global (L2-resident
// hi/lo planes) -> phase 2 is barrier-free, compiler pipelines across K-steps.
// 48 KB LDS -> 3 blocks/CU. MFMA order per accumulator unchanged (bit-exact).
__global__ __launch_bounds__(256, 3) void fused_proj_kv_kernel(
    const float* __restrict__ patch,
    const unsigned short* __restrict__ Wphi, const unsigned short* __restrict__ Wplo,
    const unsigned short* __restrict__ Wkhi, const unsigned short* __restrict__ Wklo,
    const unsigned short* __restrict__ Wvhi, const unsigned short* __restrict__ Wvlo,
    const float* __restrict__ biasp, const float* __restrict__ g_in,
    const float* __restrict__ b_in, const float* __restrict__ biask,
    const float* __restrict__ biasv,
    float* __restrict__ kout, float* __restrict__ vout)
{
    // us layout: X hi [0,8192) X lo [8192,16384) | A stage hi [16384,20480)
    //            A stage lo [20480,24576)   (total 48 KB)
    __shared__ __align__(16) unsigned short mem[24576];

    const int tid  = threadIdx.x;
    const int lane = tid & 63, wave = tid >> 6;
    const int ln15 = lane & 15, quad = lane >> 4;
    const int m0   = blockIdx.x * 64;
    const int wrow = wave * 16;                 // wave owns 16 rows throughout

    // ---------------- phase 1: X = LN(patch @ Wp^T + bp) ----------------
    f32x4 acc1[8];
#pragma unroll
    for (int nt = 0; nt < 8; nt++)
#pragma unroll
        for (int r = 0; r < 4; r++) acc1[nt][r] = 0.f;

    // A staging: super-steps of 64 k; thread stages 2 chunks of 8 floats.
    const int ar0 = tid >> 3, ak8 = tid & 7;    // chunk rows ar0, ar0+32
    const float* ap0 = patch + (size_t)(m0 + ar0) * 192 + ak8 * 8;
    const float* ap1 = patch + (size_t)(m0 + ar0 + 32) * 192 + ak8 * 8;

    float4 pa[2][2];
    pa[0][0] = *(const float4*)ap0; pa[0][1] = *(const float4*)(ap0 + 4);
    pa[1][0] = *(const float4*)ap1; pa[1][1] = *(const float4*)(ap1 + 4);

#pragma unroll
    for (int ss = 0; ss < 3; ss++) {
        // split + store staged A chunks (XOR-swizzled 64-wide rows)
#pragma unroll
        for (int i = 0; i < 2; i++) {
            float va[8] = {pa[i][0].x, pa[i][0].y, pa[i][0].z, pa[i][0].w,
                           pa[i][1].x, pa[i][1].y, pa[i][1].z, pa[i][1].w};
            us8 h, l;
#pragma unroll
            for (int j = 0; j < 8; j++) {
                unsigned int bits = __float_as_uint(va[j]);
                h[j] = (unsigned short)(bits >> 16);
                l[j] = f2b_rne(va[j] - __uint_as_float(bits & 0xffff0000u));
            }
            int row = ar0 + i * 32;
            int e = row * 64 + ((ak8 ^ (row & 7)) << 3);
            *(us8*)&mem[16384 + e] = h;
            *(us8*)&mem[20480 + e] = l;
        }
        __syncthreads();

        if (ss < 2) { // prefetch next super-step's A
            int kn = (ss + 1) * 64;
            pa[0][0] = *(const float4*)(ap0 + kn); pa[0][1] = *(const float4*)(ap0 + kn + 4);
            pa[1][0] = *(const float4*)(ap1 + kn); pa[1][1] = *(const float4*)(ap1 + kn + 4);
        }

#pragma unroll
        for (int kh = 0; kh < 2; kh++) {
            int row = wrow + ln15;
            int k8q = kh * 4 + quad;
            int ea = row * 64 + ((k8q ^ (row & 7)) << 3);
            bf16x8 ah = *(const bf16x8*)&mem[16384 + ea];
            bf16x8 al = *(const bf16x8*)&mem[20480 + ea];
            int kgl = ss * 64 + kh * 32 + quad * 8;
#pragma unroll
            for (int nt = 0; nt < 8; nt++) {
                size_t wo = (size_t)(nt * 16 + ln15) * 192 + kgl;
                bf16x8 bh = *(const bf16x8*)(Wphi + wo);
                bf16x8 bl = *(const bf16x8*)(Wplo + wo);
                acc1[nt] = __builtin_amdgcn_mfma_f32_16x16x32_bf16(ah, bh, acc1[nt], 0, 0, 0);
                acc1[nt] = __builtin_amdgcn_mfma_f32_16x16x32_bf16(ah, bl, acc1[nt], 0, 0, 0);
                acc1[nt] = __builtin_amdgcn_mfma_f32_16x16x32_bf16(al, bh, acc1[nt], 0, 0, 0);
            }
        }
        __syncthreads(); // protect A stage before next super-step rewrite
    }

    // ---- LN epilogue -> X hi/lo into LDS ----
    {
        float bb[8], gg[8], be[8];
#pragma unroll
        for (int nt = 0; nt < 8; nt++) {
            int col = nt * 16 + ln15;
            bb[nt] = biasp[col]; gg[nt] = g_in[col]; be[nt] = b_in[col];
        }
#pragma unroll
        for (int nt = 0; nt < 8; nt++)
#pragma unroll
            for (int r = 0; r < 4; r++) acc1[nt][r] += bb[nt];

        float mu[4], rs[4];
#pragma unroll
        for (int r = 0; r < 4; r++) {
            float s = 0.f, s2 = 0.f;
#pragma unroll
            for (int nt = 0; nt < 8; nt++) {
                float v = acc1[nt][r];
                s += v; s2 += v * v;
            }
#pragma unroll
            for (int off = 1; off < 16; off <<= 1) {
                s  += __shfl_xor(s,  off, 64);
                s2 += __shfl_xor(s2, off, 64);
            }
            float m = s * (1.f / 128.f);
            mu[r] = m;
            rs[r] = rsqrtf(s2 * (1.f / 128.f) - m * m + EPS);
        }
#pragma unroll
        for (int nt = 0; nt < 8; nt++)
#pragma unroll
            for (int r = 0; r < 4; r++) {
                float v = (acc1[nt][r] - mu[r]) * rs[r] * gg[nt] + be[nt];
                int row = wrow + quad * 4 + r, col = nt * 16 + ln15;
                int xi = (row * 128 + col) ^ ((row & 7) << 3);
                unsigned int bits = __float_as_uint(v);
                mem[xi]        = (unsigned short)(bits >> 16);
                mem[8192 + xi] = f2b_rne(v - __uint_as_float(bits & 0xffff0000u));
            }
    }
    __syncthreads(); // X ready -- LAST barrier; phase 2 is barrier-free

    // ---------------- phase 2: k,v = X @ {Wk,Wv}^T (no barriers) ----------
    f32x4 acck[8], accv[8];
#pragma unroll
    for (int nt = 0; nt < 8; nt++)
#pragma unroll
        for (int r = 0; r < 4; r++) { acck[nt][r] = 0.f; accv[nt][r] = 0.f; }

#pragma unroll
    for (int ks = 0; ks < 4; ks++) {
        int kk = ks * 32;
        int row = wrow + ln15;
        int ei = (row * 128 + kk + quad * 8) ^ ((row & 7) << 3);
        bf16x8 xh = *(const bf16x8*)&mem[ei];
        bf16x8 xl = *(const bf16x8*)&mem[8192 + ei];
#pragma unroll
        for (int nt = 0; nt < 8; nt++) {
            size_t wo = (size_t)(nt * 16 + ln15) * 128 + kk + quad * 8;
            bf16x8 wkh = *(const bf16x8*)(Wkhi + wo);
            bf16x8 wkl = *(const bf16x8*)(Wklo + wo);
            bf16x8 wvh = *(const bf16x8*)(Wvhi + wo);
            bf16x8 wvl = *(const bf16x8*)(Wvlo + wo);
            acck[nt] = __builtin_amdgcn_mfma_f32_16x16x32_bf16(xh, wkh, acck[nt], 0, 0, 0);
            acck[nt] = __builtin_amdgcn_mfma_f32_16x16x32_bf16(xh, wkl, acck[nt], 0, 0, 0);
            acck[nt] = __builtin_amdgcn_mfma_f32_16x16x32_bf16(xl, wkh, acck[nt], 0, 0, 0);
            accv[nt] = __builtin_amdgcn_mfma_f32_16x16x32_bf16(xh, wvh, accv[nt], 0, 0, 0);
            accv[nt] = __builtin_amdgcn_mfma_f32_16x16x32_bf16(xh, wvl, accv[nt], 0, 0, 0);
            accv[nt] = __builtin_amdgcn_mfma_f32_16x16x32_bf16(xl, wvh, accv[nt], 0, 0, 0);
        }
    }

    // ---- epilogue: bias -> store k, v ----
#pragma unroll
    for (int nt = 0; nt < 8; nt++) {
        int col = nt * 16 + ln15;
        float bk_ = biask[col], bv_ = biasv[col];
#pragma unroll
        for (int r = 0; r < 4; r++) {
            size_t o = (size_t)(m0 + wrow + quad * 4 + r) * 128 + col;
            kout[o] = acck[nt][r] + bk_;
            vout[o] = accv[nt][r] + bv_;
        }
    }
}

// =================== init slots + LN + q (one block per slot row) ============
__global__ __launch_bounds__(128) void init_lnq_kernel(
    const float* __restrict__ noise, const float* __restrict__ smu,
    const float* __restrict__ sls, const float* __restrict__ g_s,
    const float* __restrict__ b_s, const float4* __restrict__ WqT4,
    const float* __restrict__ bq, float* __restrict__ slots,
    float* __restrict__ q)
{
    __shared__ float s_l[128];
    __shared__ float red[4];
    const int row = blockIdx.x, tid = threadIdx.x;
    const int k = row % 3;
    float x = smu[k * 128 + tid] + expf(sls[k * 128 + tid]) * noise[row * 128 + tid];
    slots[row * 128 + tid] = x;

    float s = x, s2 = x * x;
#pragma unroll
    for (int off = 32; off >= 1; off >>= 1) {
        s += __shfl_down(s, off, 64); s2 += __shfl_down(s2, off, 64);
    }
    if ((tid & 63) == 0) { red[tid >> 6] = s; red[2 + (tid >> 6)] = s2; }
    __syncthreads();
    float S = red[0] + red[1], S2 = red[2] + red[3];
    float m = S * (1.f / 128.f);
    float r = rsqrtf(S2 * (1.f / 128.f) - m * m + EPS);
    s_l[tid] = (x - m) * r * g_s[tid] + b_s[tid];
    __syncthreads();

    float a = bq[tid];
#pragma unroll 8
    for (int kq = 0; kq < 32; kq++) {
        float4 w = WqT4[kq * 128 + tid];
        a += s_l[4 * kq] * w.x + s_l[4 * kq + 1] * w.y
           + s_l[4 * kq + 2] * w.z + s_l[4 * kq + 3] * w.w;
    }
    q[row * 128 + tid] = a;
}

// ============ fused attention: logits -> softmax(K=3) -> partial updates =====
// 128-token chunks, grid (8, B). v preloaded to regs d-major (issued before
// the q barrier -> latency hidden); logits stream k coalesced; PV uses all
// 256 threads with float4 FMAs; in-block partial reduce -> 1 write/chunk.
__global__ __launch_bounds__(256, 3) void attn_kernel(
    const float* __restrict__ q, const float* __restrict__ kbuf,
    const float* __restrict__ vbuf, float* __restrict__ upd_part,
    float* __restrict__ attn_out, int write_attn)
{
    __shared__ float q_l[3][132];
    __shared__ float lg[3][128];
    __shared__ float w_l[3][128];
    __shared__ float part[8][3][128];
    const int b = blockIdx.y, chunk = blockIdx.x, n0 = chunk * 128, tid = threadIdx.x;

    for (int idx = tid; idx < 384; idx += 256) {
        int s = idx >> 7, c = idx & 127;
        q_l[s][c + (c >> 5)] = q[b * 384 + idx];
    }

    // v -> regs, d-major: thread owns 4 d-cols x 16 tokens (issued early)
    const int tg = tid >> 5, d0 = (tid & 31) * 4;
    const float* vp = vbuf + ((size_t)b * 1024 + n0 + tg * 16) * 128 + d0;
    float4 vreg[16];
#pragma unroll
    for (int j = 0; j < 16; j++) vreg[j] = *(const float4*)(vp + (size_t)j * 128);

    __syncthreads(); // q_l ready

    { // logits: thread = (token n = tid>>1, half h = tid&1); k streamed
        const int n = tid >> 1, h = tid & 1;
        const float4* kp = (const float4*)(kbuf + ((size_t)b * 1024 + n0 + n) * 128 + h * 64);
        float p0 = 0.f, p1 = 0.f, p2 = 0.f;
#pragma unroll
        for (int jj = 0; jj < 2; jj++) {
            const float* q0 = &q_l[0][h * 66 + jj * 33];
            const float* q1 = &q_l[1][h * 66 + jj * 33];
            const float* q2 = &q_l[2][h * 66 + jj * 33];
#pragma unroll
            for (int f = 0; f < 8; f++) {
                float4 kk4 = kp[jj * 8 + f];
                float kx[4] = {kk4.x, kk4.y, kk4.z, kk4.w};
#pragma unroll
                for (int e = 0; e < 4; e++) {
                    float vv = kx[e];
                    p0 += q0[f * 4 + e] * vv;
                    p1 += q1[f * 4 + e] * vv;
                    p2 += q2[f * 4 + e] * vv;
                }
            }
        }
        p0 += __shfl_xor(p0, 1, 64);
        p1 += __shfl_xor(p1, 1, 64);
        p2 += __shfl_xor(p2, 1, 64);
        if (h == 0) {
            lg[0][n] = p0 * SCALE; lg[1][n] = p1 * SCALE; lg[2][n] = p2 * SCALE;
        }
    }
    __syncthreads();

    if (tid < 128) { // softmax over the 3 slots for token tid
        float l0 = lg[0][tid], l1 = lg[1][tid], l2 = lg[2][tid];
        float m = fmaxf(l0, fmaxf(l1, l2));
        float e0 = expf(l0 - m), e1 = expf(l1 - m), e2 = expf(l2 - m);
        float inv = 1.f / (e0 + e1 + e2);
        w_l[0][tid] = e0 * inv; w_l[1][tid] = e1 * inv; w_l[2][tid] = e2 * inv;
        if (write_attn) {
            int n = n0 + tid;
            attn_out[b * 3072 + n]        = e0 * inv;
            attn_out[b * 3072 + 1024 + n] = e1 * inv;
            attn_out[b * 3072 + 2048 + n] = e2 * inv;
        }
    }
    __syncthreads();

    { // PV: all 256 threads; float4 accumulate over 16 tokens
        float4 a0 = {0.f, 0.f, 0.f, 0.f}, a1 = a0, a2 = a0;
#pragma unroll
        for (int j = 0; j < 16; j++) {
            float w0 = w_l[0][tg * 16 + j];
            float w1 = w_l[1][tg * 16 + j];
            float w2 = w_l[2][tg * 16 + j];
            float4 vv = vreg[j];
            a0.x += w0 * vv.x; a0.y += w0 * vv.y; a0.z += w0 * vv.z; a0.w += w0 * vv.w;
            a1.x += w1 * vv.x; a1.y += w1 * vv.y; a1.z += w1 * vv.z; a1.w += w1 * vv.w;
            a2.x += w2 * vv.x; a2.y += w2 * vv.y; a2.z += w2 * vv.z; a2.w += w2 * vv.w;
        }
        *(float4*)&part[tg][0][d0] = a0;
        *(float4*)&part[tg][1][d0] = a1;
        *(float4*)&part[tg][2][d0] = a2;
    }
    __syncthreads();

    for (int idx = tid; idx < 384; idx += 256) { // reduce 8 groups -> global
        int s = idx >> 7, d = idx & 127;
        float u = 0.f;
#pragma unroll
        for (int g = 0; g < 8; g++) u += part[g][s][d];
        upd_part[(((size_t)b * 8 + chunk) * 3 + s) * 128 + d] = u;
    }
}

// ====== fused GRU cell + LN + MLP residual + (LN_s + q for next iter) ========
__global__ __launch_bounds__(384) void gru_mlp_kernel(
    const float* __restrict__ slots_in, const float* __restrict__ upd_part,
    const float4* __restrict__ WihT4, const float* __restrict__ bih,
    const float4* __restrict__ WhhT4, const float* __restrict__ bhh,
    const float* __restrict__ g_m, const float* __restrict__ b_m,
    const float4* __restrict__ W1T4, const float* __restrict__ b1,
    const float4* __restrict__ W2T4, const float* __restrict__ b2,
    const float* __restrict__ g_s, const float* __restrict__ b_s,
    const float4* __restrict__ WqT4, const float* __restrict__ bq,
    float* __restrict__ slots_out, float* __restrict__ q_out, int write_q)
{
    __shared__ float u2[2][128];
    __shared__ float u_l[128], h_l[128];
    __shared__ float r_l[128], z_l[128], in_l[128], hn_l[128];
    __shared__ float n_l[128], hid_l[256], w2p[256];
    __shared__ float red[4];
    const int row = blockIdx.x, tid = threadIdx.x;
    const int bb_ = row / 3, ss = row - bb_ * 3;

    if (tid < 256) {
        int col = tid & 127, half = tid >> 7;
        const float* up = upd_part + (((size_t)bb_ * 8 + half * 4) * 3 + ss) * 128 + col;
        float u = 0.f;
#pragma unroll
        for (int c = 0; c < 4; c++) u += up[(size_t)c * 384];
        u2[half][col] = u;
        if (half == 0) h_l[col] = slots_in[row * 128 + col];
    }
    __syncthreads();
    if (tid < 128) u_l[tid] = u2[0][tid] + u2[1][tid];
    __syncthreads();

    { // gates: thread t computes Wih-dot and Whh-dot for gate-output t
        float gi = bih[tid], gh = bhh[tid];
#pragma unroll 8
        for (int kq = 0; kq < 32; kq++) {
            float4 a = WihT4[kq * 384 + tid];
            float4 c = WhhT4[kq * 384 + tid];
            gi += u_l[4 * kq] * a.x + u_l[4 * kq + 1] * a.y
                + u_l[4 * kq + 2] * a.z + u_l[4 * kq + 3] * a.w;
            gh += h_l[4 * kq] * c.x + h_l[4 * kq + 1] * c.y
                + h_l[4 * kq + 2] * c.z + h_l[4 * kq + 3] * c.w;
        }
        if (tid < 128)      r_l[tid] = 1.f / (1.f + expf(-(gi + gh)));
        else if (tid < 256) z_l[tid - 128] = 1.f / (1.f + expf(-(gi + gh)));
        else { in_l[tid - 256] = gi; hn_l[tid - 256] = gh; }
    }
    __syncthreads();

    float hnew = 0.f;
    if (tid < 128) {
        float nn = tanhf(in_l[tid] + r_l[tid] * hn_l[tid]);
        hnew = (1.f - z_l[tid]) * nn + z_l[tid] * h_l[tid];
        float s = hnew, s2 = hnew * hnew;
#pragma unroll
        for (int off = 32; off >= 1; off >>= 1) {
            s += __shfl_down(s, off, 64); s2 += __shfl_down(s2, off, 64);
        }
        if ((tid & 63) == 0) { red[tid >> 6] = s; red[2 + (tid >> 6)] = s2; }
    }
    __syncthreads();
    if (tid < 128) {
        float S = red[0] + red[1], S2 = red[2] + red[3];
        float m1 = S * (1.f / 128.f);
        float r1 = rsqrtf(S2 * (1.f / 128.f) - m1 * m1 + EPS);
        n_l[tid] = (hnew - m1) * r1 * g_m[tid] + b_m[tid];
    }
    __syncthreads();

    if (tid < 256) { // W1 + gelu
        float a = b1[tid];
#pragma unroll 8
        for (int kq = 0; kq < 32; kq++) {
            float4 w = W1T4[kq * 256 + tid];
            a += n_l[4 * kq] * w.x + n_l[4 * kq + 1] * w.y
               + n_l[4 * kq + 2] * w.z + n_l[4 * kq + 3] * w.w;
        }
        a = 0.5f * a * (1.f + erff(a * 0.70710678118654752f));
        hid_l[tid] = a;
    }
    __syncthreads();

    if (tid < 256) { // W2, K=256 split in halves
        int out = tid & 127, half = tid >> 7;
        float p = 0.f;
#pragma unroll 8
        for (int kq = half * 32; kq < half * 32 + 32; kq++) {
            float4 w = W2T4[kq * 128 + out];
            p += hid_l[4 * kq] * w.x + hid_l[4 * kq + 1] * w.y
               + hid_l[4 * kq + 2] * w.z + hid_l[4 * kq + 3] * w.w;
        }
        w2p[tid] = p;
    }
    __syncthreads();

    float snew = 0.f;
    if (tid < 128) {
        snew = hnew + b2[tid] + (w2p[tid] + w2p[128 + tid]);
        slots_out[row * 128 + tid] = snew;
    }

    if (write_q) {
        if (tid < 128) {
            float t1 = snew, t2 = snew * snew;
#pragma unroll
            for (int off = 32; off >= 1; off >>= 1) {
                t1 += __shfl_down(t1, off, 64); t2 += __shfl_down(t2, off, 64);
            }
            if ((tid & 63) == 0) { red[tid >> 6] = t1; red[2 + (tid >> 6)] = t2; }
        }
        __syncthreads();
        if (tid < 128) {
            float T = red[0] + red[1], T2 = red[2] + red[3];
            float m2 = T * (1.f / 128.f);
            float r2 = rsqrtf(T2 * (1.f / 128.f) - m2 * m2 + EPS);
            n_l[tid] = (snew - m2) * r2 * g_s[tid] + b_s[tid];
        }
        __syncthreads();
        if (tid < 256) { // Wq, K=128 split in halves
            int out = tid & 127, half = tid >> 7;
            float p = (half == 0) ? bq[out] : 0.f;
#pragma unroll 8
            for (int kq = half * 16; kq < half * 16 + 16; kq++) {
                float4 w = WqT4[kq * 128 + out];
                p += n_l[4 * kq] * w.x + n_l[4 * kq + 1] * w.y
                   + n_l[4 * kq + 2] * w.z + n_l[4 * kq + 3] * w.w;
            }
            w2p[tid] = p;
        }
        __syncthreads();
        if (tid < 128) q_out[row * 128 + tid] = w2p[tid] + w2p[128 + tid];
    }
}

// ============================================================================
extern "C" void kernel_launch(void* const* d_in, const int* in_sizes, int n_in,
                              void* d_out, int out_size, void* d_ws, size_t ws_size,
                              hipStream_t stream)
{
    const float* patch   = (const float*)d_in[0];
    const float* noise   = (const float*)d_in[1];
    const float* slot_mu = (const float*)d_in[2];
    const float* slot_ls = (const float*)d_in[3];
    const float* Wp = (const float*)d_in[4];  const float* bp = (const float*)d_in[5];
    const float* g_in = (const float*)d_in[6]; const float* b_in = (const float*)d_in[7];
    const float* Wq = (const float*)d_in[8];  const float* bq = (const float*)d_in[9];
    const float* Wk = (const float*)d_in[10]; const float* bk = (const float*)d_in[11];
    const float* Wv = (const float*)d_in[12]; const float* bv = (const float*)d_in[13];
    const float* Wih = (const float*)d_in[14]; const float* bih = (const float*)d_in[15];
    const float* Whh = (const float*)d_in[16]; const float* bhh = (const float*)d_in[17];
    const float* g_s = (const float*)d_in[18]; const float* b_s = (const float*)d_in[19];
    const float* W1 = (const float*)d_in[20]; const float* b1 = (const float*)d_in[21];
    const float* W2 = (const float*)d_in[22]; const float* b2 = (const float*)d_in[23];
    const float* g_m = (const float*)d_in[24]; const float* b_m = (const float*)d_in[25];

    // ---- workspace layout ----
    float* kbuf = (float*)d_ws;                                   // 16777216 f32
    float* vbuf = kbuf + 16777216;                                // 16777216 f32
    unsigned short* w_hi = (unsigned short*)(vbuf + 16777216);    // 57344
    unsigned short* w_lo = w_hi + 57344;                          // 57344
    unsigned short* wp_hi = w_hi,        * wp_lo = w_lo;
    unsigned short* wk_hi = w_hi + 24576,* wk_lo = w_lo + 24576;
    unsigned short* wv_hi = w_hi + 40960,* wv_lo = w_lo + 40960;
    float4* wt4 = (float4*)(w_lo + 57344);                        // 45056 float4
    float4* wihT4 = wt4;
    float4* whhT4 = wt4 + 12288;
    float4* w1T4  = wt4 + 24576;
    float4* w2T4  = wt4 + 32768;
    float4* wqT4  = wt4 + 40960;
    float* slots = (float*)(wt4 + 45056);                         // 49152 f32
    float* qbuf  = slots + 49152;                                 // 49152 f32
    float* part  = qbuf + 49152;                                  // 393216 f32

    float* out_slots = (float*)d_out;                             // (B,K,H)
    float* out_attn  = (float*)d_out + 49152;                     // (B,K,N)

    prep_weights_kernel<<<400, 256, 0, stream>>>(
        Wp, Wk, Wv, Wih, Whh, W1, W2, Wq, w_hi, w_lo, wt4);

    // X = LN(patch @ Wp^T + bp) kept in LDS; k,v written directly.
    fused_proj_kv_kernel<<<2048, 256, 0, stream>>>(
        patch, wp_hi, wp_lo, wk_hi, wk_lo, wv_hi, wv_lo,
        bp, g_in, b_in, bk, bv, kbuf, vbuf);

    // slots init + LN + q0
    init_lnq_kernel<<<384, 128, 0, stream>>>(noise, slot_mu, slot_ls,
                                             g_s, b_s, wqT4, bq, slots, qbuf);

    for (int it = 0; it < 3; it++) {
        attn_kernel<<<dim3(8, 128), 256, 0, stream>>>(
            qbuf, kbuf, vbuf, part, out_attn, it == 2 ? 1 : 0);
        gru_mlp_kernel<<<384, 384, 0, stream>>>(
            slots, part, wihT4, bih, whhT4, bhh, g_m, b_m, w1T4, b1, w2T4, b2,
            g_s, b_s, wqT4, bq,
            (it == 2) ? out_slots : slots, qbuf, it == 2 ? 0 : 1);
    }
}

// Round 6
// 365.234 us; speedup vs baseline: 2.0620x; 1.5344x over previous
//
#include <hip/hip_runtime.h>
#include <math.h>

constexpr float EPS = 1e-5f;
constexpr float SCALE = 0.08838834764831845f; // 1/sqrt(128)

using f32x4  = __attribute__((ext_vector_type(4))) float;
using bf16x8 = __attribute__((ext_vector_type(8))) short;
using us8    = __attribute__((ext_vector_type(8))) unsigned short;

__device__ __forceinline__ unsigned short f2b_rne(float f) {
    unsigned int x = __float_as_uint(f);
    return (unsigned short)((x + 0x7fffu + ((x >> 16) & 1u)) >> 16);
}

// XOR-swizzled element offset into a [rows][32]-us tile; k8 = 8-elem col chunk.
__device__ __forceinline__ int swz32(int row, int k8) {
    int f = (row & 3) ^ ((row >> 2) & 3);
    return row * 32 + ((k8 ^ f) << 3);
}

// ====== one-time weight prep: bf16 hi/lo split (Wp|Wk|Wv) + float4 T-pack ====
__global__ __launch_bounds__(256) void prep_weights_kernel(
    const float* __restrict__ Wp, const float* __restrict__ Wk,
    const float* __restrict__ Wv, const float* __restrict__ Wih,
    const float* __restrict__ Whh, const float* __restrict__ W1,
    const float* __restrict__ W2, const float* __restrict__ Wq,
    unsigned short* __restrict__ hi, unsigned short* __restrict__ lo,
    float4* __restrict__ wt4)
{
    int idx = blockIdx.x * 256 + threadIdx.x; // 102400 total
    if (idx < 57344) {
        float v;
        if (idx < 24576)      v = Wp[idx];
        else if (idx < 40960) v = Wk[idx - 24576];
        else                  v = Wv[idx - 40960];
        unsigned int bits = __float_as_uint(v);
        hi[idx] = (unsigned short)(bits >> 16);
        lo[idx] = f2b_rne(v - __uint_as_float(bits & 0xffff0000u));
    } else {
        int li = idx - 57344;
        const float* src; int OUT, base, K;
        if (li < 12288)      { src = Wih; OUT = 384; base = 0;     K = 128; }
        else if (li < 24576) { src = Whh; OUT = 384; base = 12288; K = 128; }
        else if (li < 32768) { src = W1;  OUT = 256; base = 24576; K = 128; }
        else if (li < 40960) { src = W2;  OUT = 128; base = 32768; K = 256; }
        else                 { src = Wq;  OUT = 128; base = 40960; K = 128; }
        int lo2 = li - base;
        int kq = lo2 / OUT, t = lo2 - kq * OUT;
        float4 v;
        v.x = src[(size_t)t * K + 4 * kq];
        v.y = src[(size_t)t * K + 4 * kq + 1];
        v.z = src[(size_t)t * K + 4 * kq + 2];
        v.w = src[(size_t)t * K + 4 * kq + 3];
        wt4[li] = v;
    }
}

// ========== mega-fused: X = LN(patch @ Wp^T + bp); k,v = X @ {Wk,Wv}^T =======
// R3 verified structure (LDS-staged weights, 48 KB, 3 blocks/CU) +
// (i) whole patch tile preloaded to registers (A-load latency off the
//     critical path of all 6 phase-1 steps), (ii) XCD-aware block swizzle.
__global__ __launch_bounds__(256, 3) void fused_proj_kv_kernel(
    const float* __restrict__ patch,
    const unsigned short* __restrict__ Wphi, const unsigned short* __restrict__ Wplo,
    const unsigned short* __restrict__ Wkhi, const unsigned short* __restrict__ Wklo,
    const unsigned short* __restrict__ Wvhi, const unsigned short* __restrict__ Wvlo,
    const float* __restrict__ biasp, const float* __restrict__ g_in,
    const float* __restrict__ b_in, const float* __restrict__ biask,
    const float* __restrict__ biasv,
    float* __restrict__ kout, float* __restrict__ vout)
{
    // mem layout (48 KB):
    //  phase 1: Ah[0,2048) Al[2048,4096) Bh[4096,8192) Bl[8192,12288)
    //  X (after phase 1): Xh[0,8192) Xl[8192,16384)
    //  phase 2 weights: Wh[16384,20480) Wl[20480,24576)
    __shared__ __align__(16) unsigned short mem[24576];

    const int tid  = threadIdx.x;
    const int lane = tid & 63, wave = tid >> 6;
    const int ln15 = lane & 15, quad = lane >> 4;
    // XCD-aware swizzle: 2048 % 8 == 0 -> bijective
    const int bid  = blockIdx.x;
    const int m0   = ((bid & 7) * 256 + (bid >> 3)) * 64;

    // ---------------- phase 1: X = LN(patch @ Wp^T + bp) ----------------
    const int wrow = wave * 16;                 // wave owns 16 rows
    f32x4 acc1[8];
#pragma unroll
    for (int nt = 0; nt < 8; nt++)
#pragma unroll
        for (int r = 0; r < 4; r++) acc1[nt][r] = 0.f;

    const int arow = tid >> 2, ak8 = tid & 3;   // A: 1 chunk/thread per step
    const float* aptr = patch + (size_t)(m0 + arow) * 192 + ak8 * 8;
    // preload the whole 64x192 patch tile: 12 float4/thread, one burst
    float4 pa[6][2];
#pragma unroll
    for (int t6 = 0; t6 < 6; t6++) {
        pa[t6][0] = *(const float4*)(aptr + t6 * 32);
        pa[t6][1] = *(const float4*)(aptr + t6 * 32 + 4);
    }
    us8 pbh[2], pbl[2];                          // B: 2 chunks/thread (128x32)
    int boff[2];
#pragma unroll
    for (int i = 0; i < 2; i++) {
        int c = tid + 256 * i;
        boff[i] = (c >> 2) * 192 + (c & 3) * 8;
        pbh[i] = *(const us8*)(Wphi + boff[i]);
        pbl[i] = *(const us8*)(Wplo + boff[i]);
    }

    const int ea = swz32(wrow + ln15, quad);

#pragma unroll
    for (int st = 0; st < 6; st++) {
        {
            float va[8] = {pa[st][0].x, pa[st][0].y, pa[st][0].z, pa[st][0].w,
                           pa[st][1].x, pa[st][1].y, pa[st][1].z, pa[st][1].w};
            us8 h, l;
#pragma unroll
            for (int j = 0; j < 8; j++) {
                unsigned int bits = __float_as_uint(va[j]);
                h[j] = (unsigned short)(bits >> 16);
                l[j] = f2b_rne(va[j] - __uint_as_float(bits & 0xffff0000u));
            }
            int e = swz32(arow, ak8);
            *(us8*)&mem[e]        = h;
            *(us8*)&mem[2048 + e] = l;
        }
#pragma unroll
        for (int i = 0; i < 2; i++) {
            int c = tid + 256 * i;
            int e = swz32(c >> 2, c & 3);
            *(us8*)&mem[4096 + e] = pbh[i];
            *(us8*)&mem[8192 + e] = pbl[i];
        }
        __syncthreads();

        if (st < 5) { // prefetch next step's Wp tile (latency hidden by MFMAs)
            int kn = (st + 1) * 32;
#pragma unroll
            for (int i = 0; i < 2; i++) {
                pbh[i] = *(const us8*)(Wphi + boff[i] + kn);
                pbl[i] = *(const us8*)(Wplo + boff[i] + kn);
            }
        }

        bf16x8 ah = *(const bf16x8*)&mem[ea];
        bf16x8 al = *(const bf16x8*)&mem[2048 + ea];
#pragma unroll
        for (int nt = 0; nt < 8; nt++) {
            int eb = swz32(nt * 16 + ln15, quad);
            bf16x8 bh = *(const bf16x8*)&mem[4096 + eb];
            bf16x8 bl = *(const bf16x8*)&mem[8192 + eb];
            acc1[nt] = __builtin_amdgcn_mfma_f32_16x16x32_bf16(ah, bh, acc1[nt], 0, 0, 0);
            acc1[nt] = __builtin_amdgcn_mfma_f32_16x16x32_bf16(ah, bl, acc1[nt], 0, 0, 0);
            acc1[nt] = __builtin_amdgcn_mfma_f32_16x16x32_bf16(al, bh, acc1[nt], 0, 0, 0);
        }
        __syncthreads();
    }

    // prefetch phase-2 step-0 weights (k-pass, kk=0): latency hides under LN
    us8 pw[4];
#pragma unroll
    for (int i = 0; i < 4; i++) {
        const unsigned short* pl = (i >> 1) ? Wklo : Wkhi;
        int c = tid + (i & 1) * 256;
        pw[i] = *(const us8*)(pl + (size_t)(c >> 2) * 128 + (c & 3) * 8);
    }

    // ---- LN epilogue -> X hi/lo into LDS (aliases dead phase-1 staging) ----
    {
        float bb[8], gg[8], be[8];
#pragma unroll
        for (int nt = 0; nt < 8; nt++) {
            int col = nt * 16 + ln15;
            bb[nt] = biasp[col]; gg[nt] = g_in[col]; be[nt] = b_in[col];
        }
#pragma unroll
        for (int nt = 0; nt < 8; nt++)
#pragma unroll
            for (int r = 0; r < 4; r++) acc1[nt][r] += bb[nt];

        float mu[4], rs[4];
#pragma unroll
        for (int r = 0; r < 4; r++) {
            float s = 0.f, s2 = 0.f;
#pragma unroll
            for (int nt = 0; nt < 8; nt++) {
                float v = acc1[nt][r];
                s += v; s2 += v * v;
            }
#pragma unroll
            for (int off = 1; off < 16; off <<= 1) {
                s  += __shfl_xor(s,  off, 64);
                s2 += __shfl_xor(s2, off, 64);
            }
            float m = s * (1.f / 128.f);
            mu[r] = m;
            rs[r] = rsqrtf(s2 * (1.f / 128.f) - m * m + EPS);
        }
#pragma unroll
        for (int nt = 0; nt < 8; nt++)
#pragma unroll
            for (int r = 0; r < 4; r++) {
                float v = (acc1[nt][r] - mu[r]) * rs[r] * gg[nt] + be[nt];
                int row = wrow + quad * 4 + r, col = nt * 16 + ln15;
                int xi = (row * 128 + col) ^ ((row & 7) << 3);
                unsigned int bits = __float_as_uint(v);
                mem[xi]        = (unsigned short)(bits >> 16);
                mem[8192 + xi] = f2b_rne(v - __uint_as_float(bits & 0xffff0000u));
            }
    }

    // ---------------- phase 2: k-pass (s=0..3) then v-pass (s=4..7) -------
    const int R  = (wave & 1) * 32;
    const int Cb = (wave >> 1) * 64;
    const int xorx = (ln15 & 7) << 3;

    float bbk[4], bbv[4];
#pragma unroll
    for (int nt = 0; nt < 4; nt++) {
        int col = Cb + nt * 16 + ln15;
        bbk[nt] = biask[col];
        bbv[nt] = biasv[col];
    }

    f32x4 acc[2][4];
#pragma unroll
    for (int mt = 0; mt < 2; mt++)
#pragma unroll
        for (int nt = 0; nt < 4; nt++)
#pragma unroll
            for (int r = 0; r < 4; r++) acc[mt][nt][r] = 0.f;

#pragma unroll
    for (int s = 0; s < 8; s++) {
#pragma unroll
        for (int i = 0; i < 4; i++) {
            int c = tid + (i & 1) * 256;
            int e = 16384 + (i >> 1) * 4096 + swz32(c >> 2, c & 3);
            *(us8*)&mem[e] = pw[i];
        }
        __syncthreads();

        if (s < 7) {
            int sn = s + 1, kkn = (sn & 3) * 32;
            const unsigned short* ph = (sn >> 2) ? Wvhi : Wkhi;
            const unsigned short* po = (sn >> 2) ? Wvlo : Wklo;
#pragma unroll
            for (int i = 0; i < 4; i++) {
                const unsigned short* pl = (i >> 1) ? po : ph;
                int c = tid + (i & 1) * 256;
                pw[i] = *(const us8*)(pl + (size_t)(c >> 2) * 128 + (c & 3) * 8 + kkn);
            }
        }

        int kk = (s & 3) * 32;
        bf16x8 xh[2], xl[2];
#pragma unroll
        for (int mt = 0; mt < 2; mt++) {
            int row = R + mt * 16 + ln15;
            int ei = (row * 128 + kk + quad * 8) ^ xorx;
            xh[mt] = *(const bf16x8*)&mem[ei];
            xl[mt] = *(const bf16x8*)&mem[8192 + ei];
        }
#pragma unroll
        for (int nt = 0; nt < 4; nt++) {
            int eb = 16384 + swz32(Cb + nt * 16 + ln15, quad);
            bf16x8 wh = *(const bf16x8*)&mem[eb];
            bf16x8 wl = *(const bf16x8*)&mem[4096 + eb];
#pragma unroll
            for (int mt = 0; mt < 2; mt++) {
                acc[mt][nt] = __builtin_amdgcn_mfma_f32_16x16x32_bf16(xh[mt], wh, acc[mt][nt], 0, 0, 0);
                acc[mt][nt] = __builtin_amdgcn_mfma_f32_16x16x32_bf16(xh[mt], wl, acc[mt][nt], 0, 0, 0);
                acc[mt][nt] = __builtin_amdgcn_mfma_f32_16x16x32_bf16(xl[mt], wh, acc[mt][nt], 0, 0, 0);
            }
        }

        if (s == 3) { // k epilogue; reuse accumulators for v
#pragma unroll
            for (int mt = 0; mt < 2; mt++)
#pragma unroll
                for (int nt = 0; nt < 4; nt++)
#pragma unroll
                    for (int r = 0; r < 4; r++) {
                        size_t o = (size_t)(m0 + R + mt * 16 + quad * 4 + r) * 128
                                 + Cb + nt * 16 + ln15;
                        kout[o] = acc[mt][nt][r] + bbk[nt];
                        acc[mt][nt][r] = 0.f;
                    }
        }
        if (s < 7) __syncthreads();
    }

#pragma unroll
    for (int mt = 0; mt < 2; mt++)
#pragma unroll
        for (int nt = 0; nt < 4; nt++)
#pragma unroll
            for (int r = 0; r < 4; r++) {
                size_t o = (size_t)(m0 + R + mt * 16 + quad * 4 + r) * 128
                         + Cb + nt * 16 + ln15;
                vout[o] = acc[mt][nt][r] + bbv[nt];
            }
}

// =================== init slots + LN + q (one block per slot row) ============
__global__ __launch_bounds__(128) void init_lnq_kernel(
    const float* __restrict__ noise, const float* __restrict__ smu,
    const float* __restrict__ sls, const float* __restrict__ g_s,
    const float* __restrict__ b_s, const float4* __restrict__ WqT4,
    const float* __restrict__ bq, float* __restrict__ slots,
    float* __restrict__ q)
{
    __shared__ float s_l[128];
    __shared__ float red[4];
    const int row = blockIdx.x, tid = threadIdx.x;
    const int k = row % 3;
    float x = smu[k * 128 + tid] + expf(sls[k * 128 + tid]) * noise[row * 128 + tid];
    slots[row * 128 + tid] = x;

    float s = x, s2 = x * x;
#pragma unroll
    for (int off = 32; off >= 1; off >>= 1) {
        s += __shfl_down(s, off, 64); s2 += __shfl_down(s2, off, 64);
    }
    if ((tid & 63) == 0) { red[tid >> 6] = s; red[2 + (tid >> 6)] = s2; }
    __syncthreads();
    float S = red[0] + red[1], S2 = red[2] + red[3];
    float m = S * (1.f / 128.f);
    float r = rsqrtf(S2 * (1.f / 128.f) - m * m + EPS);
    s_l[tid] = (x - m) * r * g_s[tid] + b_s[tid];
    __syncthreads();

    float a = bq[tid];
#pragma unroll 8
    for (int kq = 0; kq < 32; kq++) {
        float4 w = WqT4[kq * 128 + tid];
        a += s_l[4 * kq] * w.x + s_l[4 * kq + 1] * w.y
           + s_l[4 * kq + 2] * w.z + s_l[4 * kq + 3] * w.w;
    }
    q[row * 128 + tid] = a;
}

// ============ fused attention: logits -> softmax(K=3) -> partial updates =====
// 64-token chunks, grid (16,B). k AND v in registers (coalesced, issued before
// the first barrier); logits R3-identical; PV uses ALL 256 threads (8 tokens x
// 4 cols each) with float4 FMAs; partial-reduce through small LDS.
__global__ __launch_bounds__(256) void attn_kernel(
    const float* __restrict__ q, const float* __restrict__ kbuf,
    const float* __restrict__ vbuf, float* __restrict__ upd_part,
    float* __restrict__ attn_out, int write_attn)
{
    __shared__ float q_l[3][132];
    __shared__ float lg[3][64];
    __shared__ float w_l[3][64];
    __shared__ float part[8][3][128];
    const int b = blockIdx.y, chunk = blockIdx.x, n0 = chunk * 64, tid = threadIdx.x;

    for (int idx = tid; idx < 384; idx += 256) {
        int s = idx >> 7, c = idx & 127;
        q_l[s][c + (c >> 5)] = q[b * 384 + idx];
    }

    // v -> regs, d-major: group tg (8 tokens), thread owns 4 cols x 8 tokens
    const int tg = tid >> 5, d0 = (tid & 31) * 4;
    const float* vp = vbuf + ((size_t)b * 1024 + n0 + tg * 8) * 128 + d0;
    float4 vreg[8];
#pragma unroll
    for (int j = 0; j < 8; j++) vreg[j] = *(const float4*)(vp + (size_t)j * 128);

    // k -> regs (R3 logits layout): thread = (token n, quarter q4)
    const int n = tid >> 2, q4 = tid & 3;
    float4 kr[8];
    const float4* kg4 = (const float4*)(kbuf + ((size_t)b * 1024 + n0 + n) * 128 + q4 * 32);
#pragma unroll
    for (int i = 0; i < 8; i++) kr[i] = kg4[i];
    __syncthreads();

    { // logits (identical accumulation order to R3)
        const float* q0 = &q_l[0][q4 * 33];
        const float* q1 = &q_l[1][q4 * 33];
        const float* q2 = &q_l[2][q4 * 33];
        float p0 = 0.f, p1 = 0.f, p2 = 0.f;
#pragma unroll
        for (int i = 0; i < 8; i++) {
            float kx[4] = {kr[i].x, kr[i].y, kr[i].z, kr[i].w};
#pragma unroll
            for (int j = 0; j < 4; j++) {
                float vv = kx[j];
                p0 += q0[4 * i + j] * vv;
                p1 += q1[4 * i + j] * vv;
                p2 += q2[4 * i + j] * vv;
            }
        }
        p0 += __shfl_xor(p0, 1, 64); p0 += __shfl_xor(p0, 2, 64);
        p1 += __shfl_xor(p1, 1, 64); p1 += __shfl_xor(p1, 2, 64);
        p2 += __shfl_xor(p2, 1, 64); p2 += __shfl_xor(p2, 2, 64);
        if (q4 == 0) {
            lg[0][n] = p0 * SCALE; lg[1][n] = p1 * SCALE; lg[2][n] = p2 * SCALE;
        }
    }
    __syncthreads();

    if (tid < 64) { // softmax over the 3 slots for token n=tid
        float l0 = lg[0][tid], l1 = lg[1][tid], l2 = lg[2][tid];
        float m = fmaxf(l0, fmaxf(l1, l2));
        float e0 = expf(l0 - m), e1 = expf(l1 - m), e2 = expf(l2 - m);
        float inv = 1.f / (e0 + e1 + e2);
        w_l[0][tid] = e0 * inv; w_l[1][tid] = e1 * inv; w_l[2][tid] = e2 * inv;
        if (write_attn) {
            attn_out[b * 3072 + n0 + tid]        = e0 * inv;
            attn_out[b * 3072 + 1024 + n0 + tid] = e1 * inv;
            attn_out[b * 3072 + 2048 + n0 + tid] = e2 * inv;
        }
    }
    __syncthreads();

    { // PV: all 256 threads, float4 accumulate over 8 tokens
        float4 a0 = {0.f, 0.f, 0.f, 0.f}, a1 = a0, a2 = a0;
#pragma unroll
        for (int j = 0; j < 8; j++) {
            float w0 = w_l[0][tg * 8 + j];
            float w1 = w_l[1][tg * 8 + j];
            float w2 = w_l[2][tg * 8 + j];
            float4 vv = vreg[j];
            a0.x += w0 * vv.x; a0.y += w0 * vv.y; a0.z += w0 * vv.z; a0.w += w0 * vv.w;
            a1.x += w1 * vv.x; a1.y += w1 * vv.y; a1.z += w1 * vv.z; a1.w += w1 * vv.w;
            a2.x += w2 * vv.x; a2.y += w2 * vv.y; a2.z += w2 * vv.z; a2.w += w2 * vv.w;
        }
        *(float4*)&part[tg][0][d0] = a0;
        *(float4*)&part[tg][1][d0] = a1;
        *(float4*)&part[tg][2][d0] = a2;
    }
    __syncthreads();

    for (int idx = tid; idx < 384; idx += 256) { // reduce 8 groups -> global
        int s = idx >> 7, d = idx & 127;
        float u = 0.f;
#pragma unroll
        for (int g = 0; g < 8; g++) u += part[g][s][d];
        upd_part[(((size_t)b * 16 + chunk) * 3 + s) * 128 + d] = u;
    }
}

// ====== fused GRU cell + LN + MLP residual + (LN_s + q for next iter) ========
__global__ __launch_bounds__(384) void gru_mlp_kernel(
    const float* __restrict__ slots_in, const float* __restrict__ upd_part,
    const float4* __restrict__ WihT4, const float* __restrict__ bih,
    const float4* __restrict__ WhhT4, const float* __restrict__ bhh,
    const float* __restrict__ g_m, const float* __restrict__ b_m,
    const float4* __restrict__ W1T4, const float* __restrict__ b1,
    const float4* __restrict__ W2T4, const float* __restrict__ b2,
    const float* __restrict__ g_s, const float* __restrict__ b_s,
    const float4* __restrict__ WqT4, const float* __restrict__ bq,
    float* __restrict__ slots_out, float* __restrict__ q_out, int write_q)
{
    __shared__ float u2[2][128];
    __shared__ float u_l[128], h_l[128];
    __shared__ float r_l[128], z_l[128], in_l[128], hn_l[128];
    __shared__ float n_l[128], hid_l[256], w2p[256];
    __shared__ float red[4];
    const int row = blockIdx.x, tid = threadIdx.x;
    const int bb_ = row / 3, ss = row - bb_ * 3;

    if (tid < 256) {
        int col = tid & 127, half = tid >> 7;
        const float* up = upd_part + (((size_t)bb_ * 16 + half * 8) * 3 + ss) * 128 + col;
        float u = 0.f;
#pragma unroll
        for (int c = 0; c < 8; c++) u += up[(size_t)c * 384];
        u2[half][col] = u;
        if (half == 0) h_l[col] = slots_in[row * 128 + col];
    }
    __syncthreads();
    if (tid < 128) u_l[tid] = u2[0][tid] + u2[1][tid];
    __syncthreads();

    { // gates: thread t computes Wih-dot and Whh-dot for gate-output t
        float gi = bih[tid], gh = bhh[tid];
#pragma unroll 8
        for (int kq = 0; kq < 32; kq++) {
            float4 a = WihT4[kq * 384 + tid];
            float4 c = WhhT4[kq * 384 + tid];
            gi += u_l[4 * kq] * a.x + u_l[4 * kq + 1] * a.y
                + u_l[4 * kq + 2] * a.z + u_l[4 * kq + 3] * a.w;
            gh += h_l[4 * kq] * c.x + h_l[4 * kq + 1] * c.y
                + h_l[4 * kq + 2] * c.z + h_l[4 * kq + 3] * c.w;
        }
        if (tid < 128)      r_l[tid] = 1.f / (1.f + expf(-(gi + gh)));
        else if (tid < 256) z_l[tid - 128] = 1.f / (1.f + expf(-(gi + gh)));
        else { in_l[tid - 256] = gi; hn_l[tid - 256] = gh; }
    }
    __syncthreads();

    float hnew = 0.f;
    if (tid < 128) {
        float nn = tanhf(in_l[tid] + r_l[tid] * hn_l[tid]);
        hnew = (1.f - z_l[tid]) * nn + z_l[tid] * h_l[tid];
        float s = hnew, s2 = hnew * hnew;
#pragma unroll
        for (int off = 32; off >= 1; off >>= 1) {
            s += __shfl_down(s, off, 64); s2 += __shfl_down(s2, off, 64);
        }
        if ((tid & 63) == 0) { red[tid >> 6] = s; red[2 + (tid >> 6)] = s2; }
    }
    __syncthreads();
    if (tid < 128) {
        float S = red[0] + red[1], S2 = red[2] + red[3];
        float m1 = S * (1.f / 128.f);
        float r1 = rsqrtf(S2 * (1.f / 128.f) - m1 * m1 + EPS);
        n_l[tid] = (hnew - m1) * r1 * g_m[tid] + b_m[tid];
    }
    __syncthreads();

    if (tid < 256) { // W1 + gelu
        float a = b1[tid];
#pragma unroll 8
        for (int kq = 0; kq < 32; kq++) {
            float4 w = W1T4[kq * 256 + tid];
            a += n_l[4 * kq] * w.x + n_l[4 * kq + 1] * w.y
               + n_l[4 * kq + 2] * w.z + n_l[4 * kq + 3] * w.w;
        }
        a = 0.5f * a * (1.f + erff(a * 0.70710678118654752f));
        hid_l[tid] = a;
    }
    __syncthreads();

    if (tid < 256) { // W2, K=256 split in halves
        int out = tid & 127, half = tid >> 7;
        float p = 0.f;
#pragma unroll 8
        for (int kq = half * 32; kq < half * 32 + 32; kq++) {
            float4 w = W2T4[kq * 128 + out];
            p += hid_l[4 * kq] * w.x + hid_l[4 * kq + 1] * w.y
               + hid_l[4 * kq + 2] * w.z + hid_l[4 * kq + 3] * w.w;
        }
        w2p[tid] = p;
    }
    __syncthreads();

    float snew = 0.f;
    if (tid < 128) {
        snew = hnew + b2[tid] + (w2p[tid] + w2p[128 + tid]);
        slots_out[row * 128 + tid] = snew;
    }

    if (write_q) {
        if (tid < 128) {
            float t1 = snew, t2 = snew * snew;
#pragma unroll
            for (int off = 32; off >= 1; off >>= 1) {
                t1 += __shfl_down(t1, off, 64); t2 += __shfl_down(t2, off, 64);
            }
            if ((tid & 63) == 0) { red[tid >> 6] = t1; red[2 + (tid >> 6)] = t2; }
        }
        __syncthreads();
        if (tid < 128) {
            float T = red[0] + red[1], T2 = red[2] + red[3];
            float m2 = T * (1.f / 128.f);
            float r2 = rsqrtf(T2 * (1.f / 128.f) - m2 * m2 + EPS);
            n_l[tid] = (snew - m2) * r2 * g_s[tid] + b_s[tid];
        }
        __syncthreads();
        if (tid < 256) { // Wq, K=128 split in halves
            int out = tid & 127, half = tid >> 7;
            float p = (half == 0) ? bq[out] : 0.f;
#pragma unroll 8
            for (int kq = half * 16; kq < half * 16 + 16; kq++) {
                float4 w = WqT4[kq * 128 + out];
                p += n_l[4 * kq] * w.x + n_l[4 * kq + 1] * w.y
                   + n_l[4 * kq + 2] * w.z + n_l[4 * kq + 3] * w.w;
            }
            w2p[tid] = p;
        }
        __syncthreads();
        if (tid < 128) q_out[row * 128 + tid] = w2p[tid] + w2p[128 + tid];
    }
}

// ============================================================================
extern "C" void kernel_launch(void* const* d_in, const int* in_sizes, int n_in,
                              void* d_out, int out_size, void* d_ws, size_t ws_size,
                              hipStream_t stream)
{
    const float* patch   = (const float*)d_in[0];
    const float* noise   = (const float*)d_in[1];
    const float* slot_mu = (const float*)d_in[2];
    const float* slot_ls = (const float*)d_in[3];
    const float* Wp = (const float*)d_in[4];  const float* bp = (const float*)d_in[5];
    const float* g_in = (const float*)d_in[6]; const float* b_in = (const float*)d_in[7];
    const float* Wq = (const float*)d_in[8];  const float* bq = (const float*)d_in[9];
    const float* Wk = (const float*)d_in[10]; const float* bk = (const float*)d_in[11];
    const float* Wv = (const float*)d_in[12]; const float* bv = (const float*)d_in[13];
    const float* Wih = (const float*)d_in[14]; const float* bih = (const float*)d_in[15];
    const float* Whh = (const float*)d_in[16]; const float* bhh = (const float*)d_in[17];
    const float* g_s = (const float*)d_in[18]; const float* b_s = (const float*)d_in[19];
    const float* W1 = (const float*)d_in[20]; const float* b1 = (const float*)d_in[21];
    const float* W2 = (const float*)d_in[22]; const float* b2 = (const float*)d_in[23];
    const float* g_m = (const float*)d_in[24]; const float* b_m = (const float*)d_in[25];

    // ---- workspace layout ----
    float* kbuf = (float*)d_ws;                                   // 16777216 f32
    float* vbuf = kbuf + 16777216;                                // 16777216 f32
    unsigned short* w_hi = (unsigned short*)(vbuf + 16777216);    // 57344
    unsigned short* w_lo = w_hi + 57344;                          // 57344
    unsigned short* wp_hi = w_hi,        * wp_lo = w_lo;
    unsigned short* wk_hi = w_hi + 24576,* wk_lo = w_lo + 24576;
    unsigned short* wv_hi = w_hi + 40960,* wv_lo = w_lo + 40960;
    float4* wt4 = (float4*)(w_lo + 57344);                        // 45056 float4
    float4* wihT4 = wt4;
    float4* whhT4 = wt4 + 12288;
    float4* w1T4  = wt4 + 24576;
    float4* w2T4  = wt4 + 32768;
    float4* wqT4  = wt4 + 40960;
    float* slots = (float*)(wt4 + 45056);                         // 49152 f32
    float* qbuf  = slots + 49152;                                 // 49152 f32
    float* part  = qbuf + 49152;                                  // 786432 f32

    float* out_slots = (float*)d_out;                             // (B,K,H)
    float* out_attn  = (float*)d_out + 49152;                     // (B,K,N)

    prep_weights_kernel<<<400, 256, 0, stream>>>(
        Wp, Wk, Wv, Wih, Whh, W1, W2, Wq, w_hi, w_lo, wt4);

    // X = LN(patch @ Wp^T + bp) kept in LDS; k,v written directly.
    fused_proj_kv_kernel<<<2048, 256, 0, stream>>>(
        patch, wp_hi, wp_lo, wk_hi, wk_lo, wv_hi, wv_lo,
        bp, g_in, b_in, bk, bv, kbuf, vbuf);

    // slots init + LN + q0
    init_lnq_kernel<<<384, 128, 0, stream>>>(noise, slot_mu, slot_ls,
                                             g_s, b_s, wqT4, bq, slots, qbuf);

    for (int it = 0; it < 3; it++) {
        attn_kernel<<<dim3(16, 128), 256, 0, stream>>>(
            qbuf, kbuf, vbuf, part, out_attn, it == 2 ? 1 : 0);
        gru_mlp_kernel<<<384, 384, 0, stream>>>(
            slots, part, wihT4, bih, whhT4, bhh, g_m, b_m, w1T4, b1, w2T4, b2,
            g_s, b_s, wqT4, bq,
            (it == 2) ? out_slots : slots, qbuf, it == 2 ? 0 : 1);
    }
}

// Round 7
// 358.943 us; speedup vs baseline: 2.0982x; 1.0175x over previous
//
#include <hip/hip_runtime.h>
#include <math.h>

constexpr float EPS = 1e-5f;
constexpr float SCALE = 0.08838834764831845f; // 1/sqrt(128)

using f32x4  = __attribute__((ext_vector_type(4))) float;
using bf16x8 = __attribute__((ext_vector_type(8))) short;
using us8    = __attribute__((ext_vector_type(8))) unsigned short;

__device__ __forceinline__ unsigned short f2b_rne(float f) {
    unsigned int x = __float_as_uint(f);
    return (unsigned short)((x + 0x7fffu + ((x >> 16) & 1u)) >> 16);
}

// XOR-swizzled element offset into a [rows][32]-us tile; k8 = 8-elem col chunk.
__device__ __forceinline__ int swz32(int row, int k8) {
    int f = (row & 3) ^ ((row >> 2) & 3);
    return row * 32 + ((k8 ^ f) << 3);
}

// ====== one-time weight prep: bf16 hi/lo split (Wp|Wk|Wv) + float4 T-pack ====
__global__ __launch_bounds__(256) void prep_weights_kernel(
    const float* __restrict__ Wp, const float* __restrict__ Wk,
    const float* __restrict__ Wv, const float* __restrict__ Wih,
    const float* __restrict__ Whh, const float* __restrict__ W1,
    const float* __restrict__ W2, const float* __restrict__ Wq,
    unsigned short* __restrict__ hi, unsigned short* __restrict__ lo,
    float4* __restrict__ wt4)
{
    int idx = blockIdx.x * 256 + threadIdx.x; // 102400 total
    if (idx < 57344) {
        float v;
        if (idx < 24576)      v = Wp[idx];
        else if (idx < 40960) v = Wk[idx - 24576];
        else                  v = Wv[idx - 40960];
        unsigned int bits = __float_as_uint(v);
        hi[idx] = (unsigned short)(bits >> 16);
        lo[idx] = f2b_rne(v - __uint_as_float(bits & 0xffff0000u));
    } else {
        int li = idx - 57344;
        const float* src; int OUT, base, K;
        if (li < 12288)      { src = Wih; OUT = 384; base = 0;     K = 128; }
        else if (li < 24576) { src = Whh; OUT = 384; base = 12288; K = 128; }
        else if (li < 32768) { src = W1;  OUT = 256; base = 24576; K = 128; }
        else if (li < 40960) { src = W2;  OUT = 128; base = 32768; K = 256; }
        else                 { src = Wq;  OUT = 128; base = 40960; K = 128; }
        int lo2 = li - base;
        int kq = lo2 / OUT, t = lo2 - kq * OUT;
        float4 v;
        v.x = src[(size_t)t * K + 4 * kq];
        v.y = src[(size_t)t * K + 4 * kq + 1];
        v.z = src[(size_t)t * K + 4 * kq + 2];
        v.w = src[(size_t)t * K + 4 * kq + 3];
        wt4[li] = v;
    }
}

// ========== mega-fused: X = LN(patch @ Wp^T + bp); k,v = X @ {Wk,Wv}^T =======
// R6 verified version (unchanged): LDS-staged weights, whole patch tile in
// registers, XCD-aware block swizzle. 48 KB LDS -> 3 blocks/CU.
__global__ __launch_bounds__(256, 3) void fused_proj_kv_kernel(
    const float* __restrict__ patch,
    const unsigned short* __restrict__ Wphi, const unsigned short* __restrict__ Wplo,
    const unsigned short* __restrict__ Wkhi, const unsigned short* __restrict__ Wklo,
    const unsigned short* __restrict__ Wvhi, const unsigned short* __restrict__ Wvlo,
    const float* __restrict__ biasp, const float* __restrict__ g_in,
    const float* __restrict__ b_in, const float* __restrict__ biask,
    const float* __restrict__ biasv,
    float* __restrict__ kout, float* __restrict__ vout)
{
    __shared__ __align__(16) unsigned short mem[24576];

    const int tid  = threadIdx.x;
    const int lane = tid & 63, wave = tid >> 6;
    const int ln15 = lane & 15, quad = lane >> 4;
    const int bid  = blockIdx.x;
    const int m0   = ((bid & 7) * 256 + (bid >> 3)) * 64;

    const int wrow = wave * 16;
    f32x4 acc1[8];
#pragma unroll
    for (int nt = 0; nt < 8; nt++)
#pragma unroll
        for (int r = 0; r < 4; r++) acc1[nt][r] = 0.f;

    const int arow = tid >> 2, ak8 = tid & 3;
    const float* aptr = patch + (size_t)(m0 + arow) * 192 + ak8 * 8;
    float4 pa[6][2];
#pragma unroll
    for (int t6 = 0; t6 < 6; t6++) {
        pa[t6][0] = *(const float4*)(aptr + t6 * 32);
        pa[t6][1] = *(const float4*)(aptr + t6 * 32 + 4);
    }
    us8 pbh[2], pbl[2];
    int boff[2];
#pragma unroll
    for (int i = 0; i < 2; i++) {
        int c = tid + 256 * i;
        boff[i] = (c >> 2) * 192 + (c & 3) * 8;
        pbh[i] = *(const us8*)(Wphi + boff[i]);
        pbl[i] = *(const us8*)(Wplo + boff[i]);
    }

    const int ea = swz32(wrow + ln15, quad);

#pragma unroll
    for (int st = 0; st < 6; st++) {
        {
            float va[8] = {pa[st][0].x, pa[st][0].y, pa[st][0].z, pa[st][0].w,
                           pa[st][1].x, pa[st][1].y, pa[st][1].z, pa[st][1].w};
            us8 h, l;
#pragma unroll
            for (int j = 0; j < 8; j++) {
                unsigned int bits = __float_as_uint(va[j]);
                h[j] = (unsigned short)(bits >> 16);
                l[j] = f2b_rne(va[j] - __uint_as_float(bits & 0xffff0000u));
            }
            int e = swz32(arow, ak8);
            *(us8*)&mem[e]        = h;
            *(us8*)&mem[2048 + e] = l;
        }
#pragma unroll
        for (int i = 0; i < 2; i++) {
            int c = tid + 256 * i;
            int e = swz32(c >> 2, c & 3);
            *(us8*)&mem[4096 + e] = pbh[i];
            *(us8*)&mem[8192 + e] = pbl[i];
        }
        __syncthreads();

        if (st < 5) {
            int kn = (st + 1) * 32;
#pragma unroll
            for (int i = 0; i < 2; i++) {
                pbh[i] = *(const us8*)(Wphi + boff[i] + kn);
                pbl[i] = *(const us8*)(Wplo + boff[i] + kn);
            }
        }

        bf16x8 ah = *(const bf16x8*)&mem[ea];
        bf16x8 al = *(const bf16x8*)&mem[2048 + ea];
#pragma unroll
        for (int nt = 0; nt < 8; nt++) {
            int eb = swz32(nt * 16 + ln15, quad);
            bf16x8 bh = *(const bf16x8*)&mem[4096 + eb];
            bf16x8 bl = *(const bf16x8*)&mem[8192 + eb];
            acc1[nt] = __builtin_amdgcn_mfma_f32_16x16x32_bf16(ah, bh, acc1[nt], 0, 0, 0);
            acc1[nt] = __builtin_amdgcn_mfma_f32_16x16x32_bf16(ah, bl, acc1[nt], 0, 0, 0);
            acc1[nt] = __builtin_amdgcn_mfma_f32_16x16x32_bf16(al, bh, acc1[nt], 0, 0, 0);
        }
        __syncthreads();
    }

    us8 pw[4];
#pragma unroll
    for (int i = 0; i < 4; i++) {
        const unsigned short* pl = (i >> 1) ? Wklo : Wkhi;
        int c = tid + (i & 1) * 256;
        pw[i] = *(const us8*)(pl + (size_t)(c >> 2) * 128 + (c & 3) * 8);
    }

    {
        float bb[8], gg[8], be[8];
#pragma unroll
        for (int nt = 0; nt < 8; nt++) {
            int col = nt * 16 + ln15;
            bb[nt] = biasp[col]; gg[nt] = g_in[col]; be[nt] = b_in[col];
        }
#pragma unroll
        for (int nt = 0; nt < 8; nt++)
#pragma unroll
            for (int r = 0; r < 4; r++) acc1[nt][r] += bb[nt];

        float mu[4], rs[4];
#pragma unroll
        for (int r = 0; r < 4; r++) {
            float s = 0.f, s2 = 0.f;
#pragma unroll
            for (int nt = 0; nt < 8; nt++) {
                float v = acc1[nt][r];
                s += v; s2 += v * v;
            }
#pragma unroll
            for (int off = 1; off < 16; off <<= 1) {
                s  += __shfl_xor(s,  off, 64);
                s2 += __shfl_xor(s2, off, 64);
            }
            float m = s * (1.f / 128.f);
            mu[r] = m;
            rs[r] = rsqrtf(s2 * (1.f / 128.f) - m * m + EPS);
        }
#pragma unroll
        for (int nt = 0; nt < 8; nt++)
#pragma unroll
            for (int r = 0; r < 4; r++) {
                float v = (acc1[nt][r] - mu[r]) * rs[r] * gg[nt] + be[nt];
                int row = wrow + quad * 4 + r, col = nt * 16 + ln15;
                int xi = (row * 128 + col) ^ ((row & 7) << 3);
                unsigned int bits = __float_as_uint(v);
                mem[xi]        = (unsigned short)(bits >> 16);
                mem[8192 + xi] = f2b_rne(v - __uint_as_float(bits & 0xffff0000u));
            }
    }

    const int R  = (wave & 1) * 32;
    const int Cb = (wave >> 1) * 64;
    const int xorx = (ln15 & 7) << 3;

    float bbk[4], bbv[4];
#pragma unroll
    for (int nt = 0; nt < 4; nt++) {
        int col = Cb + nt * 16 + ln15;
        bbk[nt] = biask[col];
        bbv[nt] = biasv[col];
    }

    f32x4 acc[2][4];
#pragma unroll
    for (int mt = 0; mt < 2; mt++)
#pragma unroll
        for (int nt = 0; nt < 4; nt++)
#pragma unroll
            for (int r = 0; r < 4; r++) acc[mt][nt][r] = 0.f;

#pragma unroll
    for (int s = 0; s < 8; s++) {
#pragma unroll
        for (int i = 0; i < 4; i++) {
            int c = tid + (i & 1) * 256;
            int e = 16384 + (i >> 1) * 4096 + swz32(c >> 2, c & 3);
            *(us8*)&mem[e] = pw[i];
        }
        __syncthreads();

        if (s < 7) {
            int sn = s + 1, kkn = (sn & 3) * 32;
            const unsigned short* ph = (sn >> 2) ? Wvhi : Wkhi;
            const unsigned short* po = (sn >> 2) ? Wvlo : Wklo;
#pragma unroll
            for (int i = 0; i < 4; i++) {
                const unsigned short* pl = (i >> 1) ? po : ph;
                int c = tid + (i & 1) * 256;
                pw[i] = *(const us8*)(pl + (size_t)(c >> 2) * 128 + (c & 3) * 8 + kkn);
            }
        }

        int kk = (s & 3) * 32;
        bf16x8 xh[2], xl[2];
#pragma unroll
        for (int mt = 0; mt < 2; mt++) {
            int row = R + mt * 16 + ln15;
            int ei = (row * 128 + kk + quad * 8) ^ xorx;
            xh[mt] = *(const bf16x8*)&mem[ei];
            xl[mt] = *(const bf16x8*)&mem[8192 + ei];
        }
#pragma unroll
        for (int nt = 0; nt < 4; nt++) {
            int eb = 16384 + swz32(Cb + nt * 16 + ln15, quad);
            bf16x8 wh = *(const bf16x8*)&mem[eb];
            bf16x8 wl = *(const bf16x8*)&mem[4096 + eb];
#pragma unroll
            for (int mt = 0; mt < 2; mt++) {
                acc[mt][nt] = __builtin_amdgcn_mfma_f32_16x16x32_bf16(xh[mt], wh, acc[mt][nt], 0, 0, 0);
                acc[mt][nt] = __builtin_amdgcn_mfma_f32_16x16x32_bf16(xh[mt], wl, acc[mt][nt], 0, 0, 0);
                acc[mt][nt] = __builtin_amdgcn_mfma_f32_16x16x32_bf16(xl[mt], wh, acc[mt][nt], 0, 0, 0);
            }
        }

        if (s == 3) {
#pragma unroll
            for (int mt = 0; mt < 2; mt++)
#pragma unroll
                for (int nt = 0; nt < 4; nt++)
#pragma unroll
                    for (int r = 0; r < 4; r++) {
                        size_t o = (size_t)(m0 + R + mt * 16 + quad * 4 + r) * 128
                                 + Cb + nt * 16 + ln15;
                        kout[o] = acc[mt][nt][r] + bbk[nt];
                        acc[mt][nt][r] = 0.f;
                    }
        }
        if (s < 7) __syncthreads();
    }

#pragma unroll
    for (int mt = 0; mt < 2; mt++)
#pragma unroll
        for (int nt = 0; nt < 4; nt++)
#pragma unroll
            for (int r = 0; r < 4; r++) {
                size_t o = (size_t)(m0 + R + mt * 16 + quad * 4 + r) * 128
                         + Cb + nt * 16 + ln15;
                vout[o] = acc[mt][nt][r] + bbv[nt];
            }
}

// =================== init slots + LN + q (one block per slot row) ============
__global__ __launch_bounds__(128) void init_lnq_kernel(
    const float* __restrict__ noise, const float* __restrict__ smu,
    const float* __restrict__ sls, const float* __restrict__ g_s,
    const float* __restrict__ b_s, const float4* __restrict__ WqT4,
    const float* __restrict__ bq, float* __restrict__ slots,
    float* __restrict__ q)
{
    __shared__ float s_l[128];
    __shared__ float red[4];
    const int row = blockIdx.x, tid = threadIdx.x;
    const int k = row % 3;
    float x = smu[k * 128 + tid] + expf(sls[k * 128 + tid]) * noise[row * 128 + tid];
    slots[row * 128 + tid] = x;

    float s = x, s2 = x * x;
#pragma unroll
    for (int off = 32; off >= 1; off >>= 1) {
        s += __shfl_down(s, off, 64); s2 += __shfl_down(s2, off, 64);
    }
    if ((tid & 63) == 0) { red[tid >> 6] = s; red[2 + (tid >> 6)] = s2; }
    __syncthreads();
    float S = red[0] + red[1], S2 = red[2] + red[3];
    float m = S * (1.f / 128.f);
    float r = rsqrtf(S2 * (1.f / 128.f) - m * m + EPS);
    s_l[tid] = (x - m) * r * g_s[tid] + b_s[tid];
    __syncthreads();

    float a = bq[tid];
#pragma unroll 8
    for (int kq = 0; kq < 32; kq++) {
        float4 w = WqT4[kq * 128 + tid];
        a += s_l[4 * kq] * w.x + s_l[4 * kq + 1] * w.y
           + s_l[4 * kq + 2] * w.z + s_l[4 * kq + 3] * w.w;
    }
    q[row * 128 + tid] = a;
}

// ============ fused attention: logits -> softmax(K=3) -> partial updates =====
// 256-token chunks, grid (4,B). Phase-separated: (1) logits over 4 sub-chunks
// with register-dbuf'd k, zero barriers inside; (2) softmax for all 256 tokens
// with all 256 threads; (3) PV with register-dbuf'd v, zero barriers inside.
// 4 barriers/block, 4x fewer blocks than R6 -> 16x fewer barrier drains.
__global__ __launch_bounds__(256) void attn_kernel(
    const float* __restrict__ q, const float* __restrict__ kbuf,
    const float* __restrict__ vbuf, float* __restrict__ upd_part,
    float* __restrict__ attn_out, int write_attn)
{
    __shared__ float q_l[3][132];
    __shared__ float lg[3][256];
    __shared__ float w_l[3][256];
    __shared__ float part[8][3][128];
    const int b = blockIdx.y, chunk = blockIdx.x, n0 = chunk * 256, tid = threadIdx.x;

    for (int idx = tid; idx < 384; idx += 256) {
        int s = idx >> 7, c = idx & 127;
        q_l[s][c + (c >> 5)] = q[b * 384 + idx];
    }

    // k stream base: thread = (token n = tid>>2 within sub-chunk, quarter q4)
    const int n = tid >> 2, q4 = tid & 3;
    const float4* kg4 = (const float4*)(kbuf + ((size_t)b * 1024 + n0 + n) * 128 + q4 * 32);
    // v stream base: thread owns 4 d-cols x 8 tokens per sub-chunk
    const int tg = tid >> 5, d0 = (tid & 31) * 4;
    const float* vp = vbuf + ((size_t)b * 1024 + n0 + tg * 8) * 128 + d0;

    float4 ka[8], kb2[8], va[8], vb2[8];
#pragma unroll
    for (int i = 0; i < 8; i++) ka[i] = kg4[i];     // sub-chunk 0 k
    __syncthreads();                                 // q_l ready

    // ---- phase 1: logits, 4 sub-chunks, k double-buffered ----
    const float* q0 = &q_l[0][q4 * 33];
    const float* q1 = &q_l[1][q4 * 33];
    const float* q2 = &q_l[2][q4 * 33];
#pragma unroll
    for (int sc = 0; sc < 4; sc++) {
        if (sc < 3) { // prefetch next sub-chunk's k into the alternate buffer
            const float4* kn = kg4 + (size_t)(sc + 1) * 2048;
#pragma unroll
            for (int i = 0; i < 8; i++) ((sc & 1) ? ka : kb2)[i] = kn[i];
        } else {      // last sub-chunk: issue the v prologue instead
#pragma unroll
            for (int j = 0; j < 8; j++) va[j] = *(const float4*)(vp + (size_t)j * 128);
        }
        const float4* kc = (sc & 1) ? kb2 : ka;
        float p0 = 0.f, p1 = 0.f, p2 = 0.f;
#pragma unroll
        for (int i = 0; i < 8; i++) {
            float kx[4] = {kc[i].x, kc[i].y, kc[i].z, kc[i].w};
#pragma unroll
            for (int j = 0; j < 4; j++) {
                float vv = kx[j];
                p0 += q0[4 * i + j] * vv;
                p1 += q1[4 * i + j] * vv;
                p2 += q2[4 * i + j] * vv;
            }
        }
        p0 += __shfl_xor(p0, 1, 64); p0 += __shfl_xor(p0, 2, 64);
        p1 += __shfl_xor(p1, 1, 64); p1 += __shfl_xor(p1, 2, 64);
        p2 += __shfl_xor(p2, 1, 64); p2 += __shfl_xor(p2, 2, 64);
        if (q4 == 0) {
            lg[0][sc * 64 + n] = p0 * SCALE;
            lg[1][sc * 64 + n] = p1 * SCALE;
            lg[2][sc * 64 + n] = p2 * SCALE;
        }
    }
    __syncthreads();

    // ---- phase 2: softmax over slots, token = tid (all 256 threads) ----
    {
        float l0 = lg[0][tid], l1 = lg[1][tid], l2 = lg[2][tid];
        float m = fmaxf(l0, fmaxf(l1, l2));
        float e0 = expf(l0 - m), e1 = expf(l1 - m), e2 = expf(l2 - m);
        float inv = 1.f / (e0 + e1 + e2);
        w_l[0][tid] = e0 * inv; w_l[1][tid] = e1 * inv; w_l[2][tid] = e2 * inv;
        if (write_attn) {
            int nn = n0 + tid;
            attn_out[b * 3072 + nn]        = e0 * inv;
            attn_out[b * 3072 + 1024 + nn] = e1 * inv;
            attn_out[b * 3072 + 2048 + nn] = e2 * inv;
        }
    }
    __syncthreads();

    // ---- phase 3: PV, 4 sub-chunks, v double-buffered ----
    float4 a0 = {0.f, 0.f, 0.f, 0.f}, a1 = a0, a2 = a0;
#pragma unroll
    for (int sc = 0; sc < 4; sc++) {
        if (sc < 3) { // prefetch next sub-chunk's v
            const float* vn = vp + (size_t)(sc + 1) * 8192;
#pragma unroll
            for (int j = 0; j < 8; j++)
                ((sc & 1) ? va : vb2)[j] = *(const float4*)(vn + (size_t)j * 128);
        }
        const float4* vc = (sc & 1) ? vb2 : va;
#pragma unroll
        for (int j = 0; j < 8; j++) {
            float w0 = w_l[0][sc * 64 + tg * 8 + j];
            float w1 = w_l[1][sc * 64 + tg * 8 + j];
            float w2 = w_l[2][sc * 64 + tg * 8 + j];
            float4 vv = vc[j];
            a0.x += w0 * vv.x; a0.y += w0 * vv.y; a0.z += w0 * vv.z; a0.w += w0 * vv.w;
            a1.x += w1 * vv.x; a1.y += w1 * vv.y; a1.z += w1 * vv.z; a1.w += w1 * vv.w;
            a2.x += w2 * vv.x; a2.y += w2 * vv.y; a2.z += w2 * vv.z; a2.w += w2 * vv.w;
        }
    }
    *(float4*)&part[tg][0][d0] = a0;
    *(float4*)&part[tg][1][d0] = a1;
    *(float4*)&part[tg][2][d0] = a2;
    __syncthreads();

    for (int idx = tid; idx < 384; idx += 256) { // reduce 8 groups -> global
        int s = idx >> 7, d = idx & 127;
        float u = 0.f;
#pragma unroll
        for (int g = 0; g < 8; g++) u += part[g][s][d];
        upd_part[(((size_t)b * 4 + chunk) * 3 + s) * 128 + d] = u;
    }
}

// ====== fused GRU cell + LN + MLP residual + (LN_s + q for next iter) ========
__global__ __launch_bounds__(384) void gru_mlp_kernel(
    const float* __restrict__ slots_in, const float* __restrict__ upd_part,
    const float4* __restrict__ WihT4, const float* __restrict__ bih,
    const float4* __restrict__ WhhT4, const float* __restrict__ bhh,
    const float* __restrict__ g_m, const float* __restrict__ b_m,
    const float4* __restrict__ W1T4, const float* __restrict__ b1,
    const float4* __restrict__ W2T4, const float* __restrict__ b2,
    const float* __restrict__ g_s, const float* __restrict__ b_s,
    const float4* __restrict__ WqT4, const float* __restrict__ bq,
    float* __restrict__ slots_out, float* __restrict__ q_out, int write_q)
{
    __shared__ float u2[2][128];
    __shared__ float u_l[128], h_l[128];
    __shared__ float r_l[128], z_l[128], in_l[128], hn_l[128];
    __shared__ float n_l[128], hid_l[256], w2p[256];
    __shared__ float red[4];
    const int row = blockIdx.x, tid = threadIdx.x;
    const int bb_ = row / 3, ss = row - bb_ * 3;

    if (tid < 256) {
        int col = tid & 127, half = tid >> 7;
        const float* up = upd_part + (((size_t)bb_ * 4 + half * 2) * 3 + ss) * 128 + col;
        float u = 0.f;
#pragma unroll
        for (int c = 0; c < 2; c++) u += up[(size_t)c * 384];
        u2[half][col] = u;
        if (half == 0) h_l[col] = slots_in[row * 128 + col];
    }
    __syncthreads();
    if (tid < 128) u_l[tid] = u2[0][tid] + u2[1][tid];
    __syncthreads();

    { // gates: thread t computes Wih-dot and Whh-dot for gate-output t
        float gi = bih[tid], gh = bhh[tid];
#pragma unroll 8
        for (int kq = 0; kq < 32; kq++) {
            float4 a = WihT4[kq * 384 + tid];
            float4 c = WhhT4[kq * 384 + tid];
            gi += u_l[4 * kq] * a.x + u_l[4 * kq + 1] * a.y
                + u_l[4 * kq + 2] * a.z + u_l[4 * kq + 3] * a.w;
            gh += h_l[4 * kq] * c.x + h_l[4 * kq + 1] * c.y
                + h_l[4 * kq + 2] * c.z + h_l[4 * kq + 3] * c.w;
        }
        if (tid < 128)      r_l[tid] = 1.f / (1.f + expf(-(gi + gh)));
        else if (tid < 256) z_l[tid - 128] = 1.f / (1.f + expf(-(gi + gh)));
        else { in_l[tid - 256] = gi; hn_l[tid - 256] = gh; }
    }
    __syncthreads();

    float hnew = 0.f;
    if (tid < 128) {
        float nn = tanhf(in_l[tid] + r_l[tid] * hn_l[tid]);
        hnew = (1.f - z_l[tid]) * nn + z_l[tid] * h_l[tid];
        float s = hnew, s2 = hnew * hnew;
#pragma unroll
        for (int off = 32; off >= 1; off >>= 1) {
            s += __shfl_down(s, off, 64); s2 += __shfl_down(s2, off, 64);
        }
        if ((tid & 63) == 0) { red[tid >> 6] = s; red[2 + (tid >> 6)] = s2; }
    }
    __syncthreads();
    if (tid < 128) {
        float S = red[0] + red[1], S2 = red[2] + red[3];
        float m1 = S * (1.f / 128.f);
        float r1 = rsqrtf(S2 * (1.f / 128.f) - m1 * m1 + EPS);
        n_l[tid] = (hnew - m1) * r1 * g_m[tid] + b_m[tid];
    }
    __syncthreads();

    if (tid < 256) { // W1 + gelu
        float a = b1[tid];
#pragma unroll 8
        for (int kq = 0; kq < 32; kq++) {
            float4 w = W1T4[kq * 256 + tid];
            a += n_l[4 * kq] * w.x + n_l[4 * kq + 1] * w.y
               + n_l[4 * kq + 2] * w.z + n_l[4 * kq + 3] * w.w;
        }
        a = 0.5f * a * (1.f + erff(a * 0.70710678118654752f));
        hid_l[tid] = a;
    }
    __syncthreads();

    if (tid < 256) { // W2, K=256 split in halves
        int out = tid & 127, half = tid >> 7;
        float p = 0.f;
#pragma unroll 8
        for (int kq = half * 32; kq < half * 32 + 32; kq++) {
            float4 w = W2T4[kq * 128 + out];
            p += hid_l[4 * kq] * w.x + hid_l[4 * kq + 1] * w.y
               + hid_l[4 * kq + 2] * w.z + hid_l[4 * kq + 3] * w.w;
        }
        w2p[tid] = p;
    }
    __syncthreads();

    float snew = 0.f;
    if (tid < 128) {
        snew = hnew + b2[tid] + (w2p[tid] + w2p[128 + tid]);
        slots_out[row * 128 + tid] = snew;
    }

    if (write_q) {
        if (tid < 128) {
            float t1 = snew, t2 = snew * snew;
#pragma unroll
            for (int off = 32; off >= 1; off >>= 1) {
                t1 += __shfl_down(t1, off, 64); t2 += __shfl_down(t2, off, 64);
            }
            if ((tid & 63) == 0) { red[tid >> 6] = t1; red[2 + (tid >> 6)] = t2; }
        }
        __syncthreads();
        if (tid < 128) {
            float T = red[0] + red[1], T2 = red[2] + red[3];
            float m2 = T * (1.f / 128.f);
            float r2 = rsqrtf(T2 * (1.f / 128.f) - m2 * m2 + EPS);
            n_l[tid] = (snew - m2) * r2 * g_s[tid] + b_s[tid];
        }
        __syncthreads();
        if (tid < 256) { // Wq, K=128 split in halves
            int out = tid & 127, half = tid >> 7;
            float p = (half == 0) ? bq[out] : 0.f;
#pragma unroll 8
            for (int kq = half * 16; kq < half * 16 + 16; kq++) {
                float4 w = WqT4[kq * 128 + out];
                p += n_l[4 * kq] * w.x + n_l[4 * kq + 1] * w.y
                   + n_l[4 * kq + 2] * w.z + n_l[4 * kq + 3] * w.w;
            }
            w2p[tid] = p;
        }
        __syncthreads();
        if (tid < 128) q_out[row * 128 + tid] = w2p[tid] + w2p[128 + tid];
    }
}

// ============================================================================
extern "C" void kernel_launch(void* const* d_in, const int* in_sizes, int n_in,
                              void* d_out, int out_size, void* d_ws, size_t ws_size,
                              hipStream_t stream)
{
    const float* patch   = (const float*)d_in[0];
    const float* noise   = (const float*)d_in[1];
    const float* slot_mu = (const float*)d_in[2];
    const float* slot_ls = (const float*)d_in[3];
    const float* Wp = (const float*)d_in[4];  const float* bp = (const float*)d_in[5];
    const float* g_in = (const float*)d_in[6]; const float* b_in = (const float*)d_in[7];
    const float* Wq = (const float*)d_in[8];  const float* bq = (const float*)d_in[9];
    const float* Wk = (const float*)d_in[10]; const float* bk = (const float*)d_in[11];
    const float* Wv = (const float*)d_in[12]; const float* bv = (const float*)d_in[13];
    const float* Wih = (const float*)d_in[14]; const float* bih = (const float*)d_in[15];
    const float* Whh = (const float*)d_in[16]; const float* bhh = (const float*)d_in[17];
    const float* g_s = (const float*)d_in[18]; const float* b_s = (const float*)d_in[19];
    const float* W1 = (const float*)d_in[20]; const float* b1 = (const float*)d_in[21];
    const float* W2 = (const float*)d_in[22]; const float* b2 = (const float*)d_in[23];
    const float* g_m = (const float*)d_in[24]; const float* b_m = (const float*)d_in[25];

    // ---- workspace layout ----
    float* kbuf = (float*)d_ws;                                   // 16777216 f32
    float* vbuf = kbuf + 16777216;                                // 16777216 f32
    unsigned short* w_hi = (unsigned short*)(vbuf + 16777216);    // 57344
    unsigned short* w_lo = w_hi + 57344;                          // 57344
    unsigned short* wp_hi = w_hi,        * wp_lo = w_lo;
    unsigned short* wk_hi = w_hi + 24576,* wk_lo = w_lo + 24576;
    unsigned short* wv_hi = w_hi + 40960,* wv_lo = w_lo + 40960;
    float4* wt4 = (float4*)(w_lo + 57344);                        // 45056 float4
    float4* wihT4 = wt4;
    float4* whhT4 = wt4 + 12288;
    float4* w1T4  = wt4 + 24576;
    float4* w2T4  = wt4 + 32768;
    float4* wqT4  = wt4 + 40960;
    float* slots = (float*)(wt4 + 45056);                         // 49152 f32
    float* qbuf  = slots + 49152;                                 // 49152 f32
    float* part  = qbuf + 49152;                                  // 196608 f32

    float* out_slots = (float*)d_out;                             // (B,K,H)
    float* out_attn  = (float*)d_out + 49152;                     // (B,K,N)

    prep_weights_kernel<<<400, 256, 0, stream>>>(
        Wp, Wk, Wv, Wih, Whh, W1, W2, Wq, w_hi, w_lo, wt4);

    // X = LN(patch @ Wp^T + bp) kept in LDS; k,v written directly.
    fused_proj_kv_kernel<<<2048, 256, 0, stream>>>(
        patch, wp_hi, wp_lo, wk_hi, wk_lo, wv_hi, wv_lo,
        bp, g_in, b_in, bk, bv, kbuf, vbuf);

    // slots init + LN + q0
    init_lnq_kernel<<<384, 128, 0, stream>>>(noise, slot_mu, slot_ls,
                                             g_s, b_s, wqT4, bq, slots, qbuf);

    for (int it = 0; it < 3; it++) {
        attn_kernel<<<dim3(4, 128), 256, 0, stream>>>(
            qbuf, kbuf, vbuf, part, out_attn, it == 2 ? 1 : 0);
        gru_mlp_kernel<<<384, 384, 0, stream>>>(
            slots, part, wihT4, bih, whhT4, bhh, g_m, b_m, w1T4, b1, w2T4, b2,
            g_s, b_s, wqT4, bq,
            (it == 2) ? out_slots : slots, qbuf, it == 2 ? 0 : 1);
    }
}